// Round 1
// baseline (2135.085 us; speedup 1.0000x reference)
//
#include <hip/hip_runtime.h>
#include <math.h>

#define DEVI static __device__ __forceinline__

typedef unsigned short u16;
typedef __attribute__((ext_vector_type(8))) short short8;
typedef __attribute__((ext_vector_type(4))) float f32x4;

DEVI float bf2f(u16 u) { union { float f; unsigned int i; } c; c.i = ((unsigned int)u) << 16; return c.f; }
DEVI u16 f2bf(float f) {
  union { float f; unsigned int i; } c; c.f = f;
  unsigned int r = c.i + 0x7FFFu + ((c.i >> 16) & 1u);
  return (u16)(r >> 16);
}

#define BB 64
#define LQN 128
#define LKN 1024
#define EN 768
#define HN 6
#define HDN 128
#define D2N 64
#define EPSV 1e-5f

// ---------------------------------------------------------------------------
// transpose + fp32->bf16 convert: src (K x N) row-major -> dst (N x K) bf16
__global__ __launch_bounds__(256) void transpose_cvt(
    const float* __restrict__ src, u16* __restrict__ dst, int K, int N) {
  __shared__ float tile[32][33];
  int kb = blockIdx.x * 32, nb = blockIdx.y * 32;
  int tx = threadIdx.x, ty = threadIdx.y;  // 32 x 8
  for (int j = 0; j < 32; j += 8)
    tile[ty + j][tx] = src[(size_t)(kb + ty + j) * N + nb + tx];
  __syncthreads();
  for (int j = 0; j < 32; j += 8)
    dst[(size_t)(nb + ty + j) * K + kb + tx] = f2bf(tile[tx][ty + j]);
}

// elementwise fp32 -> bf16 (4 per thread)
__global__ void conv_bf16(const float* __restrict__ src, u16* __restrict__ dst, size_t n4) {
  size_t i = (size_t)blockIdx.x * 256 + threadIdx.x;
  if (i >= n4) return;
  float4 v = ((const float4*)src)[i];
  ushort4 o;
  o.x = f2bf(v.x); o.y = f2bf(v.y); o.z = f2bf(v.z); o.w = f2bf(v.w);
  ((ushort4*)dst)[i] = o;
}

// mean-pool q_feat over LQ -> q0; also write feats slot 0
__global__ __launch_bounds__(768) void poolq_kernel(
    const float* __restrict__ qf, const float* __restrict__ qm,
    float* __restrict__ q_cur, float* __restrict__ feats) {
  int t = threadIdx.x, b = blockIdx.x;
  float s = 0.f, ms = 0.f;
  for (int l = 0; l < LQN; ++l) {
    float w = qm[b * LQN + l];
    s += qf[((size_t)b * LQN + l) * EN + t] * w;
    ms += w;
  }
  float q = s / ms;
  q_cur[(size_t)b * EN + t] = q;
  feats[(size_t)b * 3 * EN + t] = q;
}

__global__ __launch_bounds__(256) void msum_kernel(const float* __restrict__ km, float* __restrict__ msum) {
  __shared__ float red[256];
  int t = threadIdx.x, b = blockIdx.x;
  float s = 0.f;
  for (int l = t; l < LKN; l += 256) s += km[b * LKN + l];
  red[t] = s; __syncthreads();
  for (int o = 128; o > 0; o >>= 1) { if (t < o) red[t] += red[t + o]; __syncthreads(); }
  if (t == 0) msum[b] = red[0];
}

// q-side projection: out = gn(tanh(q @ W + bvec)) * g + bb   (per-head GN, HD=128)
__global__ __launch_bounds__(768) void qside_kernel(
    const float* __restrict__ q_in, const float* __restrict__ W,
    const float* __restrict__ bvec, const float* __restrict__ g,
    const float* __restrict__ bb, float* __restrict__ outp) {
  __shared__ float qs[EN];
  __shared__ float ys[EN];
  __shared__ float mh[HN], rh[HN];
  int t = threadIdx.x, b = blockIdx.x;
  qs[t] = q_in[(size_t)b * EN + t];
  __syncthreads();
  float acc = 0.f;
  for (int k = 0; k < EN; ++k) acc += qs[k] * W[(size_t)k * EN + t];
  float y = tanhf(acc + bvec[t]);
  ys[t] = y; __syncthreads();
  if (t < HN) {
    float s = 0.f, s2 = 0.f;
    for (int d = 0; d < HDN; ++d) { float v = ys[t * HDN + d]; s += v; s2 += v * v; }
    float m = s * (1.f / HDN), var = s2 * (1.f / HDN) - m * m;
    mh[t] = m; rh[t] = rsqrtf(var + EPSV);
  }
  __syncthreads();
  int h = t >> 7;
  outp[(size_t)b * EN + t] = (y - mh[h]) * rh[h] * g[t] + bb[t];
}

// qpart = q @ Wbi[0:768,:] + bbi   (no activation)
__global__ __launch_bounds__(768) void qpart_kernel(
    const float* __restrict__ q_in, const float* __restrict__ W,
    const float* __restrict__ bbi, float* __restrict__ outp) {
  __shared__ float qs[EN];
  int t = threadIdx.x, b = blockIdx.x;
  qs[t] = q_in[(size_t)b * EN + t];
  __syncthreads();
  float acc = 0.f;
  for (int k = 0; k < EN; ++k) acc += qs[k] * W[(size_t)k * EN + t];
  outp[(size_t)b * EN + t] = acc + bbi[t];
}

// ---------------------------------------------------------------------------
// big GEMM: C(M=65536 x 768) = A(M x 768 bf16) * B(768 x 768), BT is n-major.
// MODE 0: out = (gn(tanh(acc + bias[e])) * g + bb) [* scale[b,e]]  -> bf16
// MODE 1: out = relu(acc + bias[b,e]) + resid[R,e]                 -> bf16
template <int MODE>
__global__ __launch_bounds__(256) void gemm_big(
    const u16* __restrict__ A, const u16* __restrict__ BT,
    const float* __restrict__ bias, const float* __restrict__ g,
    const float* __restrict__ bb, const float* __restrict__ scale,
    const u16* __restrict__ resid, u16* __restrict__ out) {
  const int K = EN;
  __shared__ __align__(16) char smem[128 * 129 * 4];
  __shared__ float rowm[128], rowr[128];
  u16* As = (u16*)smem;             // [128][32]
  u16* Bs = (u16*)(smem + 8192);    // [128][32]
  int t = threadIdx.x;
  int w = t >> 6, lane = t & 63;
  int wm = w >> 1, wn = w & 1;
  int rowBase = blockIdx.x << 7;
  int colBase = blockIdx.y << 7;
  int r0 = t >> 2, kb = (t & 3) << 3;
  int lrow = lane & 15, kfr = (lane >> 4) << 3;

  f32x4 acc[4][4] = {};

  for (int k0 = 0; k0 < K; k0 += 32) {
    const u16* ga = A + (size_t)(rowBase + r0) * K + (k0 + kb);
    *(short8*)&As[(r0 << 5) + kb] = *(const short8*)ga;
    *(short8*)&As[((r0 + 64) << 5) + kb] = *(const short8*)(ga + (size_t)64 * K);
    const u16* gb = BT + (size_t)(colBase + r0) * K + (k0 + kb);
    *(short8*)&Bs[(r0 << 5) + kb] = *(const short8*)gb;
    *(short8*)&Bs[((r0 + 64) << 5) + kb] = *(const short8*)(gb + (size_t)64 * K);
    __syncthreads();
    short8 af[4], bf[4];
#pragma unroll
    for (int m = 0; m < 4; ++m)
      af[m] = *(const short8*)&As[((wm * 64 + m * 16 + lrow) << 5) + kfr];
#pragma unroll
    for (int n = 0; n < 4; ++n)
      bf[n] = *(const short8*)&Bs[((wn * 64 + n * 16 + lrow) << 5) + kfr];
#pragma unroll
    for (int m = 0; m < 4; ++m)
#pragma unroll
      for (int n = 0; n < 4; ++n)
        acc[m][n] = __builtin_amdgcn_mfma_f32_16x16x32_bf16(af[m], bf[n], acc[m][n], 0, 0, 0);
    __syncthreads();
  }

  if constexpr (MODE == 0) {
    float* tile = (float*)smem;  // [128][129]
#pragma unroll
    for (int m = 0; m < 4; ++m)
#pragma unroll
      for (int n = 0; n < 4; ++n)
#pragma unroll
        for (int j = 0; j < 4; ++j) {
          int r = wm * 64 + m * 16 + ((lane >> 4) << 2) + j;
          int c = wn * 64 + n * 16 + lrow;
          tile[r * 129 + c] = tanhf(acc[m][n][j] + bias[colBase + c]);
        }
    __syncthreads();
    if (t < 128) {
      float s = 0.f, s2 = 0.f;
      for (int c = 0; c < 128; ++c) { float v = tile[t * 129 + c]; s += v; s2 += v * v; }
      float m_ = s * (1.f / 128.f), var = s2 * (1.f / 128.f) - m_ * m_;
      rowm[t] = m_; rowr[t] = rsqrtf(var + EPSV);
    }
    __syncthreads();
    for (int i = t; i < 128 * 128; i += 256) {
      int r = i >> 7, c = i & 127;
      int e = colBase + c;
      size_t R = (size_t)rowBase + r;
      float v = (tile[r * 129 + c] - rowm[r]) * rowr[r] * g[e] + bb[e];
      if (scale) v *= scale[(R >> 10) * EN + e];
      out[R * EN + e] = f2bf(v);
    }
  } else {
#pragma unroll
    for (int m = 0; m < 4; ++m)
#pragma unroll
      for (int n = 0; n < 4; ++n)
#pragma unroll
        for (int j = 0; j < 4; ++j) {
          int r = wm * 64 + m * 16 + ((lane >> 4) << 2) + j;
          int c = wn * 64 + n * 16 + lrow;
          size_t R = (size_t)rowBase + r;
          int e = colBase + c;
          float y = acc[m][n][j] + bias[(R >> 10) * EN + e];
          y = fmaxf(y, 0.f) + bf2f(resid[R * EN + e]);
          out[R * EN + e] = f2bf(y);
        }
  }
}

// ---------------------------------------------------------------------------
// basic GEMM per (b,h,ltile): 128 l-rows x 64 cols, K=128.
// A = kpq rows (cols h*128..), B = WabT (64 x 128 bf16).
// Epilogue: basic = relu(acc + bab); logits s = basic . Wal + bal; pool partials.
__global__ __launch_bounds__(256) void gemm_basic(
    const u16* __restrict__ kpq, const u16* __restrict__ WabT,
    const float* __restrict__ bab, const float* __restrict__ Wal,
    const float* __restrict__ balp, const float* __restrict__ kmask,
    float* __restrict__ s_out, float* __restrict__ pool_part) {
  __shared__ __align__(16) char smem[128 * 65 * 4];
  __shared__ float km_sh[128];
  u16* As = (u16*)smem;            // [128][32]
  u16* Bs = (u16*)(smem + 8192);   // [64][32]
  int t = threadIdx.x, w = t >> 6, lane = t & 63;
  int lt = blockIdx.x, h = blockIdx.y, b = blockIdx.z;
  int lrow = lane & 15, kfr = (lane >> 4) << 3;
  int r0 = t >> 2, kb = (t & 3) << 3;
  if (t < 128) km_sh[t] = kmask[(size_t)b * LKN + lt * 128 + t];
  f32x4 acc[2][4] = {};
  size_t Abase = ((size_t)b * LKN + lt * 128) * EN + h * HDN;
  for (int k0 = 0; k0 < 128; k0 += 32) {
    *(short8*)&As[(r0 << 5) + kb] = *(const short8*)&kpq[Abase + (size_t)r0 * EN + k0 + kb];
    *(short8*)&As[((r0 + 64) << 5) + kb] = *(const short8*)&kpq[Abase + (size_t)(r0 + 64) * EN + k0 + kb];
    *(short8*)&Bs[(r0 << 5) + kb] = *(const short8*)&WabT[(size_t)r0 * 128 + k0 + kb];
    __syncthreads();
    short8 af[2], bfp[4];
#pragma unroll
    for (int m = 0; m < 2; ++m)
      af[m] = *(const short8*)&As[((w * 32 + m * 16 + lrow) << 5) + kfr];
#pragma unroll
    for (int n = 0; n < 4; ++n)
      bfp[n] = *(const short8*)&Bs[((n * 16 + lrow) << 5) + kfr];
#pragma unroll
    for (int m = 0; m < 2; ++m)
#pragma unroll
      for (int n = 0; n < 4; ++n)
        acc[m][n] = __builtin_amdgcn_mfma_f32_16x16x32_bf16(af[m], bfp[n], acc[m][n], 0, 0, 0);
    __syncthreads();
  }
  float* tile = (float*)smem;  // [128][65]
#pragma unroll
  for (int m = 0; m < 2; ++m)
#pragma unroll
    for (int n = 0; n < 4; ++n)
#pragma unroll
      for (int j = 0; j < 4; ++j) {
        int r = w * 32 + m * 16 + ((lane >> 4) << 2) + j;
        int c = n * 16 + lrow;
        tile[r * 65 + c] = fmaxf(acc[m][n][j] + bab[c], 0.f);
      }
  __syncthreads();
  if (t < 128) {
    float sum = 0.f;
    for (int c = 0; c < 64; ++c) sum += tile[t * 65 + c] * Wal[c];
    s_out[(((size_t)b * HN + h) << 10) + lt * 128 + t] = sum + balp[0];
  } else if (t < 192) {
    int c = t - 128;
    float p = 0.f;
    for (int r = 0; r < 128; ++r) p += tile[r * 65 + c] * km_sh[r];
    pool_part[((((size_t)b * HN + h) << 3) + lt) * 64 + c] = p;
  }
}

// softmax over LK (in place on s), pool finish, a_c = sigmoid(pool @ Wac + bac)
__global__ __launch_bounds__(256) void softmax_pool(
    float* __restrict__ s, const float* __restrict__ kmask,
    const float* __restrict__ msum, const float* __restrict__ pool_part,
    const float* __restrict__ Wac, const float* __restrict__ bac,
    float* __restrict__ a_c) {
  __shared__ float red[256];
  __shared__ float pool_sh[64];
  int t = threadIdx.x;
  int h = blockIdx.x, b = blockIdx.y;
  float* sb = s + (((size_t)b * HN + h) << 10);
  const float* km = kmask + (size_t)b * LKN;
  float v[4];
  float mx = -1e30f;
#pragma unroll
  for (int j = 0; j < 4; ++j) {
    int l = t * 4 + j;
    float x = sb[l];
    if (km[l] == 0.f) x = -1e9f;
    v[j] = x; mx = fmaxf(mx, x);
  }
  red[t] = mx; __syncthreads();
  for (int o = 128; o > 0; o >>= 1) { if (t < o) red[t] = fmaxf(red[t], red[t + o]); __syncthreads(); }
  float mxv = red[0];
  __syncthreads();
  float sum = 0.f;
#pragma unroll
  for (int j = 0; j < 4; ++j) { v[j] = expf(v[j] - mxv); sum += v[j]; }
  red[t] = sum; __syncthreads();
  for (int o = 128; o > 0; o >>= 1) { if (t < o) red[t] += red[t + o]; __syncthreads(); }
  float inv = 1.f / red[0];
#pragma unroll
  for (int j = 0; j < 4; ++j) sb[t * 4 + j] = v[j] * inv;
  if (t < 64) {
    float p = 0.f;
    for (int lt = 0; lt < 8; ++lt)
      p += pool_part[((((size_t)b * HN + h) << 3) + lt) * 64 + t];
    pool_sh[t] = p / msum[b];
  }
  __syncthreads();
  if (t < 128) {
    float acc = 0.f;
    for (int j = 0; j < 64; ++j) acc += pool_sh[j] * Wac[j * HDN + t];
    float x = acc + bac[t];
    a_c[(size_t)b * EN + h * HDN + t] = 1.f / (1.f + expf(-x));
  }
}

// v2a[b,h,d] = sum_l a_s[b,h,l] * v2[b*LK+l, h*128+d]
__global__ __launch_bounds__(256) void v2a_kernel(
    const float* __restrict__ a_s, const u16* __restrict__ v2,
    float* __restrict__ v2a) {
  __shared__ float part[256];
  int t = threadIdx.x;
  int d = t & 127, half = t >> 7;
  int h = blockIdx.x, b = blockIdx.y;
  const float* as = a_s + (((size_t)b * HN + h) << 10);
  const u16* vb = v2 + ((size_t)b * LKN) * EN + h * HDN + d;
  float acc = 0.f;
  for (int l = half; l < LKN; l += 2)
    acc += as[l] * bf2f(vb[(size_t)l * EN]);
  part[t] = acc; __syncthreads();
  if (t < 128) v2a[(size_t)b * EN + h * HDN + d] = part[t] + part[t + 128];
}

__global__ void qnext_kernel(
    const float* __restrict__ v1, const float* __restrict__ v2a,
    const float* __restrict__ a_c, float* __restrict__ q_cur,
    float* __restrict__ feats, int slot) {
  int idx = blockIdx.x * 256 + threadIdx.x;
  int b = idx / EN, e = idx % EN;
  float q = v1[idx] * v2a[idx] * a_c[idx];
  q_cur[idx] = q;
  feats[(size_t)b * 3 * EN + slot * EN + e] = q;
}

// row LN over 768 (bf16 in -> bf16 out)
__global__ __launch_bounds__(256) void ln_rows_kernel(
    const u16* __restrict__ z, const float* __restrict__ g,
    const float* __restrict__ bb, u16* __restrict__ outp) {
  __shared__ float red[256], red2[256];
  size_t R = blockIdx.x;
  int t = threadIdx.x;
  const u16* zr = z + R * EN;
  float x[3];
  float s = 0.f, s2 = 0.f;
#pragma unroll
  for (int j = 0; j < 3; ++j) { x[j] = bf2f(zr[j * 256 + t]); s += x[j]; s2 += x[j] * x[j]; }
  red[t] = s; red2[t] = s2; __syncthreads();
  for (int o = 128; o > 0; o >>= 1) {
    if (t < o) { red[t] += red[t + o]; red2[t] += red2[t + o]; }
    __syncthreads();
  }
  float m = red[0] * (1.f / EN), var = red2[0] * (1.f / EN) - m * m;
  float r = rsqrtf(var + EPSV);
#pragma unroll
  for (int j = 0; j < 3; ++j) {
    int e = j * 256 + t;
    outp[R * EN + e] = f2bf((x[j] - m) * r * g[e] + bb[e]);
  }
}

// final: out = ln(feats(B x 2304) @ Wp + bp)
__global__ __launch_bounds__(768) void final_kernel(
    const float* __restrict__ feats, const float* __restrict__ Wp,
    const float* __restrict__ bp, const float* __restrict__ g,
    const float* __restrict__ bb, float* __restrict__ outp) {
  __shared__ float fs[2304];
  __shared__ float red[24];
  __shared__ float mv[2];
  int t = threadIdx.x, b = blockIdx.x;
  fs[t] = feats[(size_t)b * 2304 + t];
  fs[t + 768] = feats[(size_t)b * 2304 + 768 + t];
  fs[t + 1536] = feats[(size_t)b * 2304 + 1536 + t];
  __syncthreads();
  float acc = 0.f;
  for (int k = 0; k < 2304; ++k) acc += fs[k] * Wp[(size_t)k * EN + t];
  float y = acc + bp[t];
  float s = y, s2 = y * y;
  for (int o = 32; o > 0; o >>= 1) { s += __shfl_down(s, o, 64); s2 += __shfl_down(s2, o, 64); }
  int wid = t >> 6, lane = t & 63;
  if (lane == 0) { red[wid] = s; red[12 + wid] = s2; }
  __syncthreads();
  if (t == 0) {
    float ts = 0.f, ts2 = 0.f;
    for (int i = 0; i < 12; ++i) { ts += red[i]; ts2 += red[12 + i]; }
    float m = ts * (1.f / EN), var = ts2 * (1.f / EN) - m * m;
    mv[0] = m; mv[1] = rsqrtf(var + EPSV);
  }
  __syncthreads();
  outp[(size_t)b * EN + t] = (y - mv[0]) * mv[1] * g[t] + bb[t];
}

// ---------------------------------------------------------------------------
extern "C" void kernel_launch(void* const* d_in, const int* in_sizes, int n_in,
                              void* d_out, int out_size, void* d_ws, size_t ws_size,
                              hipStream_t stream) {
  const float* q_feat = (const float*)d_in[0];
  const float* k_feats = (const float*)d_in[1];
  const float* q_mask = (const float*)d_in[2];
  const float* k_mask = (const float*)d_in[3];
  const float* Wq = (const float*)d_in[4];
  const float* bq = (const float*)d_in[5];
  const float* gq_g = (const float*)d_in[6];
  const float* gq_b = (const float*)d_in[7];
  const float* Wk = (const float*)d_in[8];
  const float* bk = (const float*)d_in[9];
  const float* gk_g = (const float*)d_in[10];
  const float* gk_b = (const float*)d_in[11];
  const float* Wv1 = (const float*)d_in[12];
  const float* bv1 = (const float*)d_in[13];
  const float* g1_g = (const float*)d_in[14];
  const float* g1_b = (const float*)d_in[15];
  const float* Wv2 = (const float*)d_in[16];
  const float* bv2 = (const float*)d_in[17];
  const float* g2_g = (const float*)d_in[18];
  const float* g2_b = (const float*)d_in[19];
  const float* Wab = (const float*)d_in[20];
  const float* bab = (const float*)d_in[21];
  const float* Wal = (const float*)d_in[22];
  const float* bal = (const float*)d_in[23];
  const float* Wac = (const float*)d_in[24];
  const float* bac = (const float*)d_in[25];
  const float* Wbi = (const float*)d_in[26];
  const float* bbi = (const float*)d_in[27];
  const float* lnb_g = (const float*)d_in[28];
  const float* lnb_b = (const float*)d_in[29];
  const float* Wp = (const float*)d_in[30];
  const float* bp = (const float*)d_in[31];
  const float* ln_g = (const float*)d_in[32];
  const float* ln_b = (const float*)d_in[33];
  float* out = (float*)d_out;
  (void)in_sizes; (void)n_in; (void)out_size; (void)ws_size;

  char* ws = (char*)d_ws;
  size_t off = 0;
  auto alloc = [&](size_t bytes) -> char* {
    char* p = ws + off;
    off += (bytes + 255) & ~(size_t)255;
    return p;
  };
  const size_t MK = (size_t)BB * LKN;  // 65536
  u16* kf = (u16*)alloc(MK * EN * 2);
  u16* kpq = (u16*)alloc(MK * EN * 2);   // also reused as z-buffer for k-update
  u16* v2b = (u16*)alloc(MK * EN * 2);
  u16* WkT = (u16*)alloc((size_t)2 * EN * EN * 2);
  u16* Wv2T = (u16*)alloc((size_t)2 * EN * EN * 2);
  u16* WbiT = (u16*)alloc((size_t)EN * EN * 2);
  u16* WabT = (u16*)alloc((size_t)2 * D2N * HDN * 2);
  float* feats = (float*)alloc((size_t)BB * 3 * EN * 4);
  float* q_cur = (float*)alloc((size_t)BB * EN * 4);
  float* qp = (float*)alloc((size_t)BB * EN * 4);
  float* v1 = (float*)alloc((size_t)BB * EN * 4);
  float* qpart = (float*)alloc((size_t)BB * EN * 4);
  float* sbuf = (float*)alloc((size_t)BB * HN * LKN * 4);
  float* poolp = (float*)alloc((size_t)BB * HN * 8 * D2N * 4);
  float* a_c = (float*)alloc((size_t)BB * EN * 4);
  float* v2a = (float*)alloc((size_t)BB * EN * 4);
  float* msum = (float*)alloc((size_t)BB * 4);

  dim3 tb(32, 8);
  // weight prep (bf16 transposed copies)
  for (int i = 0; i < 2; ++i) {
    transpose_cvt<<<dim3(EN / 32, EN / 32), tb, 0, stream>>>(Wk + (size_t)i * EN * EN, WkT + (size_t)i * EN * EN, EN, EN);
    transpose_cvt<<<dim3(EN / 32, EN / 32), tb, 0, stream>>>(Wv2 + (size_t)i * EN * EN, Wv2T + (size_t)i * EN * EN, EN, EN);
    transpose_cvt<<<dim3(HDN / 32, D2N / 32), tb, 0, stream>>>(Wab + (size_t)i * HDN * D2N, WabT + (size_t)i * D2N * HDN, HDN, D2N);
  }
  transpose_cvt<<<dim3(EN / 32, EN / 32), tb, 0, stream>>>(Wbi + (size_t)EN * EN, WbiT, EN, EN);

  conv_bf16<<<49152, 256, 0, stream>>>(k_feats, kf, MK * EN / 4);
  poolq_kernel<<<BB, EN, 0, stream>>>(q_feat, q_mask, q_cur, feats);
  msum_kernel<<<BB, 256, 0, stream>>>(k_mask, msum);

  for (int i = 0; i < 2; ++i) {
    const size_t wofs = (size_t)i * EN * EN;
    qside_kernel<<<BB, EN, 0, stream>>>(q_cur, Wq + wofs, bq + i * EN, gq_g + i * EN, gq_b + i * EN, qp);
    qside_kernel<<<BB, EN, 0, stream>>>(q_cur, Wv1 + wofs, bv1 + i * EN, g1_g + i * EN, g1_b + i * EN, v1);
    gemm_big<0><<<dim3(512, 6), 256, 0, stream>>>(kf, WkT + wofs, bk + i * EN, gk_g + i * EN, gk_b + i * EN, qp, nullptr, kpq);
    gemm_big<0><<<dim3(512, 6), 256, 0, stream>>>(kf, Wv2T + wofs, bv2 + i * EN, g2_g + i * EN, g2_b + i * EN, nullptr, nullptr, v2b);
    gemm_basic<<<dim3(8, HN, BB), 256, 0, stream>>>(kpq, WabT + (size_t)i * D2N * HDN, bab + i * D2N, Wal + i * D2N, bal + i, k_mask, sbuf, poolp);
    softmax_pool<<<dim3(HN, BB), 256, 0, stream>>>(sbuf, k_mask, msum, poolp, Wac + (size_t)i * D2N * HDN, bac + i * HDN, a_c);
    v2a_kernel<<<dim3(HN, BB), 256, 0, stream>>>(sbuf, v2b, v2a);
    qnext_kernel<<<BB * EN / 256, 256, 0, stream>>>(v1, v2a, a_c, q_cur, feats, i + 1);
    if (i == 0) {
      qpart_kernel<<<BB, EN, 0, stream>>>(q_cur, Wbi, bbi, qpart);
      gemm_big<1><<<dim3(512, 6), 256, 0, stream>>>(kf, WbiT, qpart, nullptr, nullptr, nullptr, kf, kpq);
      ln_rows_kernel<<<MK, 256, 0, stream>>>(kpq, lnb_g, lnb_b, kf);
    }
  }
  final_kernel<<<BB, EN, 0, stream>>>(feats, Wp, bp, ln_g, ln_b, out);
}

// Round 2
// 2002.938 us; speedup vs baseline: 1.0660x; 1.0660x over previous
//
#include <hip/hip_runtime.h>
#include <math.h>

#define DEVI static __device__ __forceinline__

typedef unsigned short u16;
typedef __attribute__((ext_vector_type(8))) short short8;
typedef __attribute__((ext_vector_type(4))) float f32x4;

DEVI float bf2f(u16 u) { union { float f; unsigned int i; } c; c.i = ((unsigned int)u) << 16; return c.f; }
DEVI u16 f2bf(float f) {
  union { float f; unsigned int i; } c; c.f = f;
  unsigned int r = c.i + 0x7FFFu + ((c.i >> 16) & 1u);
  return (u16)(r >> 16);
}

// async global->LDS, 16B per lane. LDS base must be wave-uniform; HW adds lane*16B.
DEVI void gld16(const u16* g, u16* l) {
  __builtin_amdgcn_global_load_lds((const __attribute__((address_space(1))) unsigned int*)g,
                                   (__attribute__((address_space(3))) unsigned int*)l, 16, 0, 0);
}

#define BB 64
#define LQN 128
#define LKN 1024
#define EN 768
#define HN 6
#define HDN 128
#define D2N 64
#define EPSV 1e-5f

// ---------------------------------------------------------------------------
// transpose + fp32->bf16 convert: src (K x N) row-major -> dst (N x K) bf16
__global__ __launch_bounds__(256) void transpose_cvt(
    const float* __restrict__ src, u16* __restrict__ dst, int K, int N) {
  __shared__ float tile[32][33];
  int kb = blockIdx.x * 32, nb = blockIdx.y * 32;
  int tx = threadIdx.x, ty = threadIdx.y;  // 32 x 8
  for (int j = 0; j < 32; j += 8)
    tile[ty + j][tx] = src[(size_t)(kb + ty + j) * N + nb + tx];
  __syncthreads();
  for (int j = 0; j < 32; j += 8)
    dst[(size_t)(nb + ty + j) * K + kb + tx] = f2bf(tile[tx][ty + j]);
}

// elementwise fp32 -> bf16 (4 per thread)
__global__ void conv_bf16(const float* __restrict__ src, u16* __restrict__ dst, size_t n4) {
  size_t i = (size_t)blockIdx.x * 256 + threadIdx.x;
  if (i >= n4) return;
  float4 v = ((const float4*)src)[i];
  ushort4 o;
  o.x = f2bf(v.x); o.y = f2bf(v.y); o.z = f2bf(v.z); o.w = f2bf(v.w);
  ((ushort4*)dst)[i] = o;
}

// mean-pool q_feat over LQ -> q0; also write feats slot 0
__global__ __launch_bounds__(768) void poolq_kernel(
    const float* __restrict__ qf, const float* __restrict__ qm,
    float* __restrict__ q_cur, float* __restrict__ feats) {
  int t = threadIdx.x, b = blockIdx.x;
  float s = 0.f, ms = 0.f;
  for (int l = 0; l < LQN; ++l) {
    float w = qm[b * LQN + l];
    s += qf[((size_t)b * LQN + l) * EN + t] * w;
    ms += w;
  }
  float q = s / ms;
  q_cur[(size_t)b * EN + t] = q;
  feats[(size_t)b * 3 * EN + t] = q;
}

__global__ __launch_bounds__(256) void msum_kernel(const float* __restrict__ km, float* __restrict__ msum) {
  __shared__ float red[256];
  int t = threadIdx.x, b = blockIdx.x;
  float s = 0.f;
  for (int l = t; l < LKN; l += 256) s += km[b * LKN + l];
  red[t] = s; __syncthreads();
  for (int o = 128; o > 0; o >>= 1) { if (t < o) red[t] += red[t + o]; __syncthreads(); }
  if (t == 0) msum[b] = red[0];
}

// q-side projection: out = gn(tanh(q @ W + bvec)) * g + bb   (per-head GN, HD=128)
__global__ __launch_bounds__(768) void qside_kernel(
    const float* __restrict__ q_in, const float* __restrict__ W,
    const float* __restrict__ bvec, const float* __restrict__ g,
    const float* __restrict__ bb, float* __restrict__ outp) {
  __shared__ float qs[EN];
  __shared__ float ys[EN];
  __shared__ float mh[HN], rh[HN];
  int t = threadIdx.x, b = blockIdx.x;
  qs[t] = q_in[(size_t)b * EN + t];
  __syncthreads();
  float acc = 0.f;
  for (int k = 0; k < EN; ++k) acc += qs[k] * W[(size_t)k * EN + t];
  float y = tanhf(acc + bvec[t]);
  ys[t] = y; __syncthreads();
  if (t < HN) {
    float s = 0.f, s2 = 0.f;
    for (int d = 0; d < HDN; ++d) { float v = ys[t * HDN + d]; s += v; s2 += v * v; }
    float m = s * (1.f / HDN), var = s2 * (1.f / HDN) - m * m;
    mh[t] = m; rh[t] = rsqrtf(var + EPSV);
  }
  __syncthreads();
  int h = t >> 7;
  outp[(size_t)b * EN + t] = (y - mh[h]) * rh[h] * g[t] + bb[t];
}

// qpart = q @ Wbi[0:768,:] + bbi   (no activation)
__global__ __launch_bounds__(768) void qpart_kernel(
    const float* __restrict__ q_in, const float* __restrict__ W,
    const float* __restrict__ bbi, float* __restrict__ outp) {
  __shared__ float qs[EN];
  int t = threadIdx.x, b = blockIdx.x;
  qs[t] = q_in[(size_t)b * EN + t];
  __syncthreads();
  float acc = 0.f;
  for (int k = 0; k < EN; ++k) acc += qs[k] * W[(size_t)k * EN + t];
  outp[(size_t)b * EN + t] = acc + bbi[t];
}

// ---------------------------------------------------------------------------
// Merged projection GEMM: C(65536 x 1536) = A(65536 x 768 bf16) * [Wk^T; Wv2^T]
// col-tiles 0..5 -> kp path (gn(tanh)*g+bb then *qp) -> out_k
// col-tiles 6..11 -> v2 path (gn(tanh)*g+bb)          -> out_v
// m97 structure: global_load_lds width-16 staging, 128x128 tile, BK=32.
__global__ __launch_bounds__(256) void gemm_proj(
    const u16* __restrict__ A, const u16* __restrict__ BT,
    const float* __restrict__ bias_k, const float* __restrict__ g_k,
    const float* __restrict__ bb_k, const float* __restrict__ qp,
    u16* __restrict__ out_k,
    const float* __restrict__ bias_v, const float* __restrict__ g_v,
    const float* __restrict__ bb_v, u16* __restrict__ out_v) {
  const int K = EN;
  __shared__ __align__(16) char smem[128 * 129 * 4];
  __shared__ float rowm[128], rowr[128];
  u16* As = (u16*)smem;             // [128][32] linear
  u16* Bs = (u16*)(smem + 8192);    // [128][32] linear
  int t = threadIdx.x;
  int w = t >> 6, lane = t & 63;
  int wm = w >> 1, wn = w & 1;

  // XCD-chunked bijective swizzle: 6144 = 8 * 768; consecutive swz share a row-tile.
  int bid = blockIdx.x;
  int swz = ((bid & 7) * 768) + (bid >> 3);
  int rowT = swz / 12, cT = swz % 12;
  int rowBase = rowT << 7;

  int srow = (w << 5) + (lane >> 2);   // staging row 0..127
  int skoff = (lane & 3) << 3;         // staging k element offset
  const u16* gA = A + (size_t)(rowBase + srow) * K + skoff;
  const u16* gB = BT + (size_t)((cT << 7) + srow) * K + skoff;
  u16* lA0 = As + ((w << 5) << 5);         // wave-uniform LDS bases
  u16* lA1 = As + (((w << 5) + 16) << 5);
  u16* lB0 = Bs + ((w << 5) << 5);
  u16* lB1 = Bs + (((w << 5) + 16) << 5);

  int lrow = lane & 15, kfr = (lane >> 4) << 3;
  f32x4 acc[4][4] = {};

  for (int k0 = 0; k0 < K; k0 += 32) {
    gld16(gA + k0, lA0);
    gld16(gA + (size_t)16 * K + k0, lA1);
    gld16(gB + k0, lB0);
    gld16(gB + (size_t)16 * K + k0, lB1);
    __syncthreads();
    short8 af[4], bf[4];
#pragma unroll
    for (int m = 0; m < 4; ++m)
      af[m] = *(const short8*)&As[((wm * 64 + m * 16 + lrow) << 5) + kfr];
#pragma unroll
    for (int n = 0; n < 4; ++n)
      bf[n] = *(const short8*)&Bs[((wn * 64 + n * 16 + lrow) << 5) + kfr];
#pragma unroll
    for (int m = 0; m < 4; ++m)
#pragma unroll
      for (int n = 0; n < 4; ++n)
        acc[m][n] = __builtin_amdgcn_mfma_f32_16x16x32_bf16(af[m], bf[n], acc[m][n], 0, 0, 0);
    __syncthreads();
  }

  const int which = cT >= 6;
  const int ecol = ((which ? cT - 6 : cT) << 7);
  const float* bias = which ? bias_v : bias_k;
  const float* g = which ? g_v : g_k;
  const float* bb = which ? bb_v : bb_k;
  u16* outp = which ? out_v : out_k;

  float* tile = (float*)smem;  // [128][129]
#pragma unroll
  for (int m = 0; m < 4; ++m)
#pragma unroll
    for (int n = 0; n < 4; ++n)
#pragma unroll
      for (int j = 0; j < 4; ++j) {
        int r = wm * 64 + m * 16 + ((lane >> 4) << 2) + j;
        int c = wn * 64 + n * 16 + lrow;
        tile[r * 129 + c] = tanhf(acc[m][n][j] + bias[ecol + c]);
      }
  __syncthreads();
  if (t < 128) {
    float s = 0.f, s2 = 0.f;
    for (int c = 0; c < 128; ++c) { float v = tile[t * 129 + c]; s += v; s2 += v * v; }
    float m_ = s * (1.f / 128.f), var = s2 * (1.f / 128.f) - m_ * m_;
    rowm[t] = m_; rowr[t] = rsqrtf(var + EPSV);
  }
  __syncthreads();
  for (int i = t; i < 128 * 128; i += 256) {
    int r = i >> 7, c = i & 127;
    int e = ecol + c;
    size_t R = (size_t)rowBase + r;
    float v = (tile[r * 129 + c] - rowm[r]) * rowr[r] * g[e] + bb[e];
    if (!which) v *= qp[(R >> 10) * EN + e];
    outp[R * EN + e] = f2bf(v);
  }
}

// Bilinear k-update GEMM: z = relu(A @ WbiT + qpart[b]) + kf  -> bf16
__global__ __launch_bounds__(256) void gemm_bilin(
    const u16* __restrict__ A, const u16* __restrict__ BT,
    const float* __restrict__ biasB, const u16* __restrict__ resid,
    u16* __restrict__ out) {
  const int K = EN;
  __shared__ __align__(16) u16 As[128 * 32];
  __shared__ __align__(16) u16 Bs[128 * 32];
  int t = threadIdx.x;
  int w = t >> 6, lane = t & 63;
  int wm = w >> 1, wn = w & 1;

  int bid = blockIdx.x;                 // 3072 = 8 * 384
  int swz = ((bid & 7) * 384) + (bid >> 3);
  int rowT = swz / 6, cT = swz % 6;
  int rowBase = rowT << 7;
  int colBase = cT << 7;

  int srow = (w << 5) + (lane >> 2);
  int skoff = (lane & 3) << 3;
  const u16* gA = A + (size_t)(rowBase + srow) * K + skoff;
  const u16* gB = BT + (size_t)(colBase + srow) * K + skoff;
  u16* lA0 = As + ((w << 5) << 5);
  u16* lA1 = As + (((w << 5) + 16) << 5);
  u16* lB0 = Bs + ((w << 5) << 5);
  u16* lB1 = Bs + (((w << 5) + 16) << 5);

  int lrow = lane & 15, kfr = (lane >> 4) << 3;
  f32x4 acc[4][4] = {};

  for (int k0 = 0; k0 < K; k0 += 32) {
    gld16(gA + k0, lA0);
    gld16(gA + (size_t)16 * K + k0, lA1);
    gld16(gB + k0, lB0);
    gld16(gB + (size_t)16 * K + k0, lB1);
    __syncthreads();
    short8 af[4], bf[4];
#pragma unroll
    for (int m = 0; m < 4; ++m)
      af[m] = *(const short8*)&As[((wm * 64 + m * 16 + lrow) << 5) + kfr];
#pragma unroll
    for (int n = 0; n < 4; ++n)
      bf[n] = *(const short8*)&Bs[((wn * 64 + n * 16 + lrow) << 5) + kfr];
#pragma unroll
    for (int m = 0; m < 4; ++m)
#pragma unroll
      for (int n = 0; n < 4; ++n)
        acc[m][n] = __builtin_amdgcn_mfma_f32_16x16x32_bf16(af[m], bf[n], acc[m][n], 0, 0, 0);
    __syncthreads();
  }

#pragma unroll
  for (int m = 0; m < 4; ++m)
#pragma unroll
    for (int n = 0; n < 4; ++n)
#pragma unroll
      for (int j = 0; j < 4; ++j) {
        int r = wm * 64 + m * 16 + ((lane >> 4) << 2) + j;
        int c = wn * 64 + n * 16 + lrow;
        size_t R = (size_t)rowBase + r;
        int e = colBase + c;
        float y = acc[m][n][j] + biasB[(R >> 10) * EN + e];
        y = fmaxf(y, 0.f) + bf2f(resid[R * EN + e]);
        out[R * EN + e] = f2bf(y);
      }
}

// ---------------------------------------------------------------------------
// basic GEMM per (b,h,ltile): 128 l-rows x 64 cols, K=128.
__global__ __launch_bounds__(256) void gemm_basic(
    const u16* __restrict__ kpq, const u16* __restrict__ WabT,
    const float* __restrict__ bab, const float* __restrict__ Wal,
    const float* __restrict__ balp, const float* __restrict__ kmask,
    float* __restrict__ s_out, float* __restrict__ pool_part) {
  __shared__ __align__(16) char smem[128 * 65 * 4];
  __shared__ float km_sh[128];
  u16* As = (u16*)smem;            // [128][32]
  u16* Bs = (u16*)(smem + 8192);   // [64][32]
  int t = threadIdx.x, w = t >> 6, lane = t & 63;
  int lt = blockIdx.x, h = blockIdx.y, b = blockIdx.z;
  int lrow = lane & 15, kfr = (lane >> 4) << 3;
  int r0 = t >> 2, kb = (t & 3) << 3;
  if (t < 128) km_sh[t] = kmask[(size_t)b * LKN + lt * 128 + t];
  f32x4 acc[2][4] = {};
  size_t Abase = ((size_t)b * LKN + lt * 128) * EN + h * HDN;
  for (int k0 = 0; k0 < 128; k0 += 32) {
    *(short8*)&As[(r0 << 5) + kb] = *(const short8*)&kpq[Abase + (size_t)r0 * EN + k0 + kb];
    *(short8*)&As[((r0 + 64) << 5) + kb] = *(const short8*)&kpq[Abase + (size_t)(r0 + 64) * EN + k0 + kb];
    *(short8*)&Bs[(r0 << 5) + kb] = *(const short8*)&WabT[(size_t)r0 * 128 + k0 + kb];
    __syncthreads();
    short8 af[2], bfp[4];
#pragma unroll
    for (int m = 0; m < 2; ++m)
      af[m] = *(const short8*)&As[((w * 32 + m * 16 + lrow) << 5) + kfr];
#pragma unroll
    for (int n = 0; n < 4; ++n)
      bfp[n] = *(const short8*)&Bs[((n * 16 + lrow) << 5) + kfr];
#pragma unroll
    for (int m = 0; m < 2; ++m)
#pragma unroll
      for (int n = 0; n < 4; ++n)
        acc[m][n] = __builtin_amdgcn_mfma_f32_16x16x32_bf16(af[m], bfp[n], acc[m][n], 0, 0, 0);
    __syncthreads();
  }
  float* tile = (float*)smem;  // [128][65]
#pragma unroll
  for (int m = 0; m < 2; ++m)
#pragma unroll
    for (int n = 0; n < 4; ++n)
#pragma unroll
      for (int j = 0; j < 4; ++j) {
        int r = w * 32 + m * 16 + ((lane >> 4) << 2) + j;
        int c = n * 16 + lrow;
        tile[r * 65 + c] = fmaxf(acc[m][n][j] + bab[c], 0.f);
      }
  __syncthreads();
  if (t < 128) {
    float sum = 0.f;
    for (int c = 0; c < 64; ++c) sum += tile[t * 65 + c] * Wal[c];
    s_out[(((size_t)b * HN + h) << 10) + lt * 128 + t] = sum + balp[0];
  } else if (t < 192) {
    int c = t - 128;
    float p = 0.f;
    for (int r = 0; r < 128; ++r) p += tile[r * 65 + c] * km_sh[r];
    pool_part[((((size_t)b * HN + h) << 3) + lt) * 64 + c] = p;
  }
}

// softmax over LK (in place on s), pool finish, a_c = sigmoid(pool @ Wac + bac)
__global__ __launch_bounds__(256) void softmax_pool(
    float* __restrict__ s, const float* __restrict__ kmask,
    const float* __restrict__ msum, const float* __restrict__ pool_part,
    const float* __restrict__ Wac, const float* __restrict__ bac,
    float* __restrict__ a_c) {
  __shared__ float red[256];
  __shared__ float pool_sh[64];
  int t = threadIdx.x;
  int h = blockIdx.x, b = blockIdx.y;
  float* sb = s + (((size_t)b * HN + h) << 10);
  const float* km = kmask + (size_t)b * LKN;
  float v[4];
  float mx = -1e30f;
#pragma unroll
  for (int j = 0; j < 4; ++j) {
    int l = t * 4 + j;
    float x = sb[l];
    if (km[l] == 0.f) x = -1e9f;
    v[j] = x; mx = fmaxf(mx, x);
  }
  red[t] = mx; __syncthreads();
  for (int o = 128; o > 0; o >>= 1) { if (t < o) red[t] = fmaxf(red[t], red[t + o]); __syncthreads(); }
  float mxv = red[0];
  __syncthreads();
  float sum = 0.f;
#pragma unroll
  for (int j = 0; j < 4; ++j) { v[j] = expf(v[j] - mxv); sum += v[j]; }
  red[t] = sum; __syncthreads();
  for (int o = 128; o > 0; o >>= 1) { if (t < o) red[t] += red[t + o]; __syncthreads(); }
  float inv = 1.f / red[0];
#pragma unroll
  for (int j = 0; j < 4; ++j) sb[t * 4 + j] = v[j] * inv;
  if (t < 64) {
    float p = 0.f;
    for (int lt = 0; lt < 8; ++lt)
      p += pool_part[((((size_t)b * HN + h) << 3) + lt) * 64 + t];
    pool_sh[t] = p / msum[b];
  }
  __syncthreads();
  if (t < 128) {
    float acc = 0.f;
    for (int j = 0; j < 64; ++j) acc += pool_sh[j] * Wac[j * HDN + t];
    float x = acc + bac[t];
    a_c[(size_t)b * EN + h * HDN + t] = 1.f / (1.f + expf(-x));
  }
}

// v2a[b,h,d] = sum_l a_s[b,h,l] * v2[b*LK+l, h*128+d]
__global__ __launch_bounds__(256) void v2a_kernel(
    const float* __restrict__ a_s, const u16* __restrict__ v2,
    float* __restrict__ v2a) {
  __shared__ float part[256];
  int t = threadIdx.x;
  int d = t & 127, half = t >> 7;
  int h = blockIdx.x, b = blockIdx.y;
  const float* as = a_s + (((size_t)b * HN + h) << 10);
  const u16* vb = v2 + ((size_t)b * LKN) * EN + h * HDN + d;
  float acc = 0.f;
  for (int l = half; l < LKN; l += 2)
    acc += as[l] * bf2f(vb[(size_t)l * EN]);
  part[t] = acc; __syncthreads();
  if (t < 128) v2a[(size_t)b * EN + h * HDN + d] = part[t] + part[t + 128];
}

__global__ void qnext_kernel(
    const float* __restrict__ v1, const float* __restrict__ v2a,
    const float* __restrict__ a_c, float* __restrict__ q_cur,
    float* __restrict__ feats, int slot) {
  int idx = blockIdx.x * 256 + threadIdx.x;
  int b = idx / EN, e = idx % EN;
  float q = v1[idx] * v2a[idx] * a_c[idx];
  q_cur[idx] = q;
  feats[(size_t)b * 3 * EN + slot * EN + e] = q;
}

// row LN over 768 (bf16 in -> bf16 out)
__global__ __launch_bounds__(256) void ln_rows_kernel(
    const u16* __restrict__ z, const float* __restrict__ g,
    const float* __restrict__ bb, u16* __restrict__ outp) {
  __shared__ float red[256], red2[256];
  size_t R = blockIdx.x;
  int t = threadIdx.x;
  const u16* zr = z + R * EN;
  float x[3];
  float s = 0.f, s2 = 0.f;
#pragma unroll
  for (int j = 0; j < 3; ++j) { x[j] = bf2f(zr[j * 256 + t]); s += x[j]; s2 += x[j] * x[j]; }
  red[t] = s; red2[t] = s2; __syncthreads();
  for (int o = 128; o > 0; o >>= 1) {
    if (t < o) { red[t] += red[t + o]; red2[t] += red2[t + o]; }
    __syncthreads();
  }
  float m = red[0] * (1.f / EN), var = red2[0] * (1.f / EN) - m * m;
  float r = rsqrtf(var + EPSV);
#pragma unroll
  for (int j = 0; j < 3; ++j) {
    int e = j * 256 + t;
    outp[R * EN + e] = f2bf((x[j] - m) * r * g[e] + bb[e]);
  }
}

// final: out = ln(feats(B x 2304) @ Wp + bp)
__global__ __launch_bounds__(768) void final_kernel(
    const float* __restrict__ feats, const float* __restrict__ Wp,
    const float* __restrict__ bp, const float* __restrict__ g,
    const float* __restrict__ bb, float* __restrict__ outp) {
  __shared__ float fs[2304];
  __shared__ float red[24];
  __shared__ float mv[2];
  int t = threadIdx.x, b = blockIdx.x;
  fs[t] = feats[(size_t)b * 2304 + t];
  fs[t + 768] = feats[(size_t)b * 2304 + 768 + t];
  fs[t + 1536] = feats[(size_t)b * 2304 + 1536 + t];
  __syncthreads();
  float acc = 0.f;
  for (int k = 0; k < 2304; ++k) acc += fs[k] * Wp[(size_t)k * EN + t];
  float y = acc + bp[t];
  float s = y, s2 = y * y;
  for (int o = 32; o > 0; o >>= 1) { s += __shfl_down(s, o, 64); s2 += __shfl_down(s2, o, 64); }
  int wid = t >> 6, lane = t & 63;
  if (lane == 0) { red[wid] = s; red[12 + wid] = s2; }
  __syncthreads();
  if (t == 0) {
    float ts = 0.f, ts2 = 0.f;
    for (int i = 0; i < 12; ++i) { ts += red[i]; ts2 += red[12 + i]; }
    float m = ts * (1.f / EN), var = ts2 * (1.f / EN) - m * m;
    mv[0] = m; mv[1] = rsqrtf(var + EPSV);
  }
  __syncthreads();
  outp[(size_t)b * EN + t] = (y - mv[0]) * mv[1] * g[t] + bb[t];
}

// ---------------------------------------------------------------------------
extern "C" void kernel_launch(void* const* d_in, const int* in_sizes, int n_in,
                              void* d_out, int out_size, void* d_ws, size_t ws_size,
                              hipStream_t stream) {
  const float* q_feat = (const float*)d_in[0];
  const float* k_feats = (const float*)d_in[1];
  const float* q_mask = (const float*)d_in[2];
  const float* k_mask = (const float*)d_in[3];
  const float* Wq = (const float*)d_in[4];
  const float* bq = (const float*)d_in[5];
  const float* gq_g = (const float*)d_in[6];
  const float* gq_b = (const float*)d_in[7];
  const float* Wk = (const float*)d_in[8];
  const float* bk = (const float*)d_in[9];
  const float* gk_g = (const float*)d_in[10];
  const float* gk_b = (const float*)d_in[11];
  const float* Wv1 = (const float*)d_in[12];
  const float* bv1 = (const float*)d_in[13];
  const float* g1_g = (const float*)d_in[14];
  const float* g1_b = (const float*)d_in[15];
  const float* Wv2 = (const float*)d_in[16];
  const float* bv2 = (const float*)d_in[17];
  const float* g2_g = (const float*)d_in[18];
  const float* g2_b = (const float*)d_in[19];
  const float* Wab = (const float*)d_in[20];
  const float* bab = (const float*)d_in[21];
  const float* Wal = (const float*)d_in[22];
  const float* bal = (const float*)d_in[23];
  const float* Wac = (const float*)d_in[24];
  const float* bac = (const float*)d_in[25];
  const float* Wbi = (const float*)d_in[26];
  const float* bbi = (const float*)d_in[27];
  const float* lnb_g = (const float*)d_in[28];
  const float* lnb_b = (const float*)d_in[29];
  const float* Wp = (const float*)d_in[30];
  const float* bp = (const float*)d_in[31];
  const float* ln_g = (const float*)d_in[32];
  const float* ln_b = (const float*)d_in[33];
  float* out = (float*)d_out;
  (void)in_sizes; (void)n_in; (void)out_size; (void)ws_size;

  char* ws = (char*)d_ws;
  size_t off = 0;
  auto alloc = [&](size_t bytes) -> char* {
    char* p = ws + off;
    off += (bytes + 255) & ~(size_t)255;
    return p;
  };
  const size_t MK = (size_t)BB * LKN;  // 65536
  u16* kf = (u16*)alloc(MK * EN * 2);
  u16* kpq = (u16*)alloc(MK * EN * 2);   // also reused as z-buffer for k-update
  u16* v2b = (u16*)alloc(MK * EN * 2);
  u16* WkvT = (u16*)alloc((size_t)2 * 1536 * EN * 2);  // per layer: [Wk^T; Wv2^T]
  u16* WbiT = (u16*)alloc((size_t)EN * EN * 2);
  u16* WabT = (u16*)alloc((size_t)2 * D2N * HDN * 2);
  float* feats = (float*)alloc((size_t)BB * 3 * EN * 4);
  float* q_cur = (float*)alloc((size_t)BB * EN * 4);
  float* qp = (float*)alloc((size_t)BB * EN * 4);
  float* v1 = (float*)alloc((size_t)BB * EN * 4);
  float* qpart = (float*)alloc((size_t)BB * EN * 4);
  float* sbuf = (float*)alloc((size_t)BB * HN * LKN * 4);
  float* poolp = (float*)alloc((size_t)BB * HN * 8 * D2N * 4);
  float* a_c = (float*)alloc((size_t)BB * EN * 4);
  float* v2a = (float*)alloc((size_t)BB * EN * 4);
  float* msum = (float*)alloc((size_t)BB * 4);

  dim3 tb(32, 8);
  // weight prep (bf16 transposed copies)
  for (int i = 0; i < 2; ++i) {
    u16* dst = WkvT + (size_t)i * 1536 * EN;
    transpose_cvt<<<dim3(EN / 32, EN / 32), tb, 0, stream>>>(Wk + (size_t)i * EN * EN, dst, EN, EN);
    transpose_cvt<<<dim3(EN / 32, EN / 32), tb, 0, stream>>>(Wv2 + (size_t)i * EN * EN, dst + (size_t)EN * EN, EN, EN);
    transpose_cvt<<<dim3(HDN / 32, D2N / 32), tb, 0, stream>>>(Wab + (size_t)i * HDN * D2N, WabT + (size_t)i * D2N * HDN, HDN, D2N);
  }
  transpose_cvt<<<dim3(EN / 32, EN / 32), tb, 0, stream>>>(Wbi + (size_t)EN * EN, WbiT, EN, EN);

  conv_bf16<<<49152, 256, 0, stream>>>(k_feats, kf, MK * EN / 4);
  poolq_kernel<<<BB, EN, 0, stream>>>(q_feat, q_mask, q_cur, feats);
  msum_kernel<<<BB, 256, 0, stream>>>(k_mask, msum);

  for (int i = 0; i < 2; ++i) {
    const size_t wofs = (size_t)i * EN * EN;
    qside_kernel<<<BB, EN, 0, stream>>>(q_cur, Wq + wofs, bq + i * EN, gq_g + i * EN, gq_b + i * EN, qp);
    qside_kernel<<<BB, EN, 0, stream>>>(q_cur, Wv1 + wofs, bv1 + i * EN, g1_g + i * EN, g1_b + i * EN, v1);
    gemm_proj<<<6144, 256, 0, stream>>>(
        kf, WkvT + (size_t)i * 1536 * EN,
        bk + i * EN, gk_g + i * EN, gk_b + i * EN, qp, kpq,
        bv2 + i * EN, g2_g + i * EN, g2_b + i * EN, v2b);
    gemm_basic<<<dim3(8, HN, BB), 256, 0, stream>>>(kpq, WabT + (size_t)i * D2N * HDN, bab + i * D2N, Wal + i * D2N, bal + i, k_mask, sbuf, poolp);
    softmax_pool<<<dim3(HN, BB), 256, 0, stream>>>(sbuf, k_mask, msum, poolp, Wac + (size_t)i * D2N * HDN, bac + i * HDN, a_c);
    v2a_kernel<<<dim3(HN, BB), 256, 0, stream>>>(sbuf, v2b, v2a);
    qnext_kernel<<<BB * EN / 256, 256, 0, stream>>>(v1, v2a, a_c, q_cur, feats, i + 1);
    if (i == 0) {
      qpart_kernel<<<BB, EN, 0, stream>>>(q_cur, Wbi, bbi, qpart);
      gemm_bilin<<<3072, 256, 0, stream>>>(kf, WbiT, qpart, kf, kpq);
      ln_rows_kernel<<<MK, 256, 0, stream>>>(kpq, lnb_g, lnb_b, kf);
    }
  }
  final_kernel<<<BB, EN, 0, stream>>>(feats, Wp, bp, ln_g, ln_b, out);
}

// Round 3
// 1511.330 us; speedup vs baseline: 1.4127x; 1.3253x over previous
//
#include <hip/hip_runtime.h>
#include <math.h>

#define DEVI static __device__ __forceinline__

typedef unsigned short u16;
typedef __attribute__((ext_vector_type(8))) short short8;
typedef __attribute__((ext_vector_type(4))) float f32x4;

DEVI float bf2f(u16 u) { union { float f; unsigned int i; } c; c.i = ((unsigned int)u) << 16; return c.f; }
DEVI u16 f2bf(float f) {
  union { float f; unsigned int i; } c; c.f = f;
  unsigned int r = c.i + 0x7FFFu + ((c.i >> 16) & 1u);
  return (u16)(r >> 16);
}

DEVI float ftanh(float x) {
  float e = __expf(2.f * x);
  return 1.f - 2.f * __builtin_amdgcn_rcpf(e + 1.f);
}

// async global->LDS, 16B per lane. LDS base must be wave-uniform; HW adds lane*16B.
DEVI void gld16(const u16* g, u16* l) {
  __builtin_amdgcn_global_load_lds((const __attribute__((address_space(1))) unsigned int*)g,
                                   (__attribute__((address_space(3))) unsigned int*)l, 16, 0, 0);
}

#define BB 64
#define LQN 128
#define LKN 1024
#define EN 768
#define HN 6
#define HDN 128
#define D2N 64
#define EPSV 1e-5f

// ---------------------------------------------------------------------------
// transpose + fp32->bf16 convert: src (K x N) row-major -> dst (N x K) bf16
__global__ __launch_bounds__(256) void transpose_cvt(
    const float* __restrict__ src, u16* __restrict__ dst, int K, int N) {
  __shared__ float tile[32][33];
  int kb = blockIdx.x * 32, nb = blockIdx.y * 32;
  int tx = threadIdx.x, ty = threadIdx.y;  // 32 x 8
  for (int j = 0; j < 32; j += 8)
    tile[ty + j][tx] = src[(size_t)(kb + ty + j) * N + nb + tx];
  __syncthreads();
  for (int j = 0; j < 32; j += 8)
    dst[(size_t)(nb + ty + j) * K + kb + tx] = f2bf(tile[tx][ty + j]);
}

// elementwise fp32 -> bf16 (4 per thread)
__global__ void conv_bf16(const float* __restrict__ src, u16* __restrict__ dst, size_t n4) {
  size_t i = (size_t)blockIdx.x * 256 + threadIdx.x;
  if (i >= n4) return;
  float4 v = ((const float4*)src)[i];
  ushort4 o;
  o.x = f2bf(v.x); o.y = f2bf(v.y); o.z = f2bf(v.z); o.w = f2bf(v.w);
  ((ushort4*)dst)[i] = o;
}

// mean-pool q_feat over LQ -> q0; also write feats slot 0
__global__ __launch_bounds__(768) void poolq_kernel(
    const float* __restrict__ qf, const float* __restrict__ qm,
    float* __restrict__ q_cur, float* __restrict__ feats) {
  int t = threadIdx.x, b = blockIdx.x;
  float s = 0.f, ms = 0.f;
  for (int l = 0; l < LQN; ++l) {
    float w = qm[b * LQN + l];
    s += qf[((size_t)b * LQN + l) * EN + t] * w;
    ms += w;
  }
  float q = s / ms;
  q_cur[(size_t)b * EN + t] = q;
  feats[(size_t)b * 3 * EN + t] = q;
}

__global__ __launch_bounds__(256) void msum_kernel(const float* __restrict__ km, float* __restrict__ msum) {
  __shared__ float red[256];
  int t = threadIdx.x, b = blockIdx.x;
  float s = 0.f;
  for (int l = t; l < LKN; l += 256) s += km[b * LKN + l];
  red[t] = s; __syncthreads();
  for (int o = 128; o > 0; o >>= 1) { if (t < o) red[t] += red[t + o]; __syncthreads(); }
  if (t == 0) msum[b] = red[0];
}

// q-side projection: out = gn(tanh(q @ W + bvec)) * g + bb   (per-head GN, HD=128)
__global__ __launch_bounds__(768) void qside_kernel(
    const float* __restrict__ q_in, const float* __restrict__ W,
    const float* __restrict__ bvec, const float* __restrict__ g,
    const float* __restrict__ bb, float* __restrict__ outp) {
  __shared__ float qs[EN];
  __shared__ float ys[EN];
  __shared__ float mh[HN], rh[HN];
  int t = threadIdx.x, b = blockIdx.x;
  qs[t] = q_in[(size_t)b * EN + t];
  __syncthreads();
  float acc = 0.f;
  for (int k = 0; k < EN; ++k) acc += qs[k] * W[(size_t)k * EN + t];
  float y = tanhf(acc + bvec[t]);
  ys[t] = y; __syncthreads();
  if (t < HN) {
    float s = 0.f, s2 = 0.f;
    for (int d = 0; d < HDN; ++d) { float v = ys[t * HDN + d]; s += v; s2 += v * v; }
    float m = s * (1.f / HDN), var = s2 * (1.f / HDN) - m * m;
    mh[t] = m; rh[t] = rsqrtf(var + EPSV);
  }
  __syncthreads();
  int h = t >> 7;
  outp[(size_t)b * EN + t] = (y - mh[h]) * rh[h] * g[t] + bb[t];
}

// qpart = q @ Wbi[0:768,:] + bbi   (no activation)
__global__ __launch_bounds__(768) void qpart_kernel(
    const float* __restrict__ q_in, const float* __restrict__ W,
    const float* __restrict__ bbi, float* __restrict__ outp) {
  __shared__ float qs[EN];
  int t = threadIdx.x, b = blockIdx.x;
  qs[t] = q_in[(size_t)b * EN + t];
  __syncthreads();
  float acc = 0.f;
  for (int k = 0; k < EN; ++k) acc += qs[k] * W[(size_t)k * EN + t];
  outp[(size_t)b * EN + t] = acc + bbi[t];
}

// ---------------------------------------------------------------------------
// Merged projection GEMM: C(65536 x 1536) = A(65536 x 768 bf16) * [Wk^T; Wv2^T]
// Double-buffered global_load_lds staging, slot-XOR LDS swizzle, shuffle-GN
// epilogue (no big LDS tile -> 34 KB LDS -> 4 blocks/CU).
__global__ __launch_bounds__(256, 4) void gemm_proj(
    const u16* __restrict__ A, const u16* __restrict__ BT,
    const float* __restrict__ bias_k, const float* __restrict__ g_k,
    const float* __restrict__ bb_k, const float* __restrict__ qp,
    u16* __restrict__ out_k,
    const float* __restrict__ bias_v, const float* __restrict__ g_v,
    const float* __restrict__ bb_v, u16* __restrict__ out_v) {
  const int K = EN;
  __shared__ __align__(16) u16 As[2 * 128 * 32];
  __shared__ __align__(16) u16 Bs[2 * 128 * 32];
  __shared__ float part[2][128][2];
  int t = threadIdx.x;
  int w = t >> 6, lane = t & 63;
  int wm = w >> 1, wn = w & 1;

  // XCD-chunked bijective swizzle: 6144 = 8 * 768
  int bid = blockIdx.x;
  int swz = ((bid & 7) * 768) + (bid >> 3);
  int rowT = swz / 12, cT = swz % 12;
  int rowBase = rowT << 7;

  // staging: lane covers row = w*32 + (lane>>2), slot = lane&3 (16B slots).
  // LDS[row][slot] holds global slot (slot ^ ((row>>1)&3))  [source pre-swizzle]
  int koff = (((lane & 3) ^ ((lane >> 3) & 3)) << 3);
  const u16* gA = A + (size_t)(rowBase + (w << 5) + (lane >> 2)) * K + koff;
  const u16* gB = BT + (size_t)((cT << 7) + (w << 5) + (lane >> 2)) * K + koff;

  int lrow = lane & 15, kq = lane >> 4;
  int sOff = ((kq ^ ((lrow >> 1) & 3)) << 3);  // swizzled k-slot for frag reads
  f32x4 acc[4][4] = {};

  // prologue: stage k0=0 into buf 0
  {
    u16* lA = As + (w << 10);
    u16* lB = Bs + (w << 10);
    gld16(gA, lA); gld16(gA + (size_t)16 * K, lA + 512);
    gld16(gB, lB); gld16(gB + (size_t)16 * K, lB + 512);
  }
  int buf = 0;
  for (int it = 0; it < 24; ++it) {
    __syncthreads();  // drains vmcnt -> buf ready
    if (it < 23) {
      int k0 = (it + 1) << 5;
      u16* lA = As + ((buf ^ 1) << 12) + (w << 10);
      u16* lB = Bs + ((buf ^ 1) << 12) + (w << 10);
      gld16(gA + k0, lA); gld16(gA + (size_t)16 * K + k0, lA + 512);
      gld16(gB + k0, lB); gld16(gB + (size_t)16 * K + k0, lB + 512);
    }
    short8 af[4], bf[4];
#pragma unroll
    for (int m = 0; m < 4; ++m)
      af[m] = *(const short8*)&As[(buf << 12) + ((wm * 64 + m * 16 + lrow) << 5) + sOff];
#pragma unroll
    for (int n = 0; n < 4; ++n)
      bf[n] = *(const short8*)&Bs[(buf << 12) + ((wn * 64 + n * 16 + lrow) << 5) + sOff];
#pragma unroll
    for (int m = 0; m < 4; ++m)
#pragma unroll
      for (int n = 0; n < 4; ++n)
        acc[m][n] = __builtin_amdgcn_mfma_f32_16x16x32_bf16(af[m], bf[n], acc[m][n], 0, 0, 0);
    buf ^= 1;
  }

  // ---- epilogue: y = tanh(acc + bias); GroupNorm over 128-col tile; write bf16
  const int which = cT >= 6;
  const int ecol = ((which ? cT - 6 : cT) << 7);
  const float* bias = which ? bias_v : bias_k;
  const float* gp = which ? g_v : g_k;
  const float* bbp = which ? bb_v : bb_k;
  u16* outp = which ? out_v : out_k;
  const int bidx = rowBase >> 10;

  float biasv[4], gv[4], bbv[4], qpv[4];
#pragma unroll
  for (int n = 0; n < 4; ++n) {
    int e = ecol + wn * 64 + n * 16 + lrow;
    biasv[n] = bias[e]; gv[n] = gp[e]; bbv[n] = bbp[e];
    qpv[n] = which ? 1.f : qp[(size_t)bidx * EN + e];
  }
#pragma unroll
  for (int m = 0; m < 4; ++m)
#pragma unroll
    for (int n = 0; n < 4; ++n)
#pragma unroll
      for (int j = 0; j < 4; ++j)
        acc[m][n][j] = ftanh(acc[m][n][j] + biasv[n]);

#pragma unroll
  for (int m = 0; m < 4; ++m)
#pragma unroll
    for (int j = 0; j < 4; ++j) {
      float s = acc[m][0][j] + acc[m][1][j] + acc[m][2][j] + acc[m][3][j];
      float s2 = acc[m][0][j] * acc[m][0][j] + acc[m][1][j] * acc[m][1][j] +
                 acc[m][2][j] * acc[m][2][j] + acc[m][3][j] * acc[m][3][j];
#pragma unroll
      for (int o = 1; o < 16; o <<= 1) {
        s += __shfl_xor(s, o, 64);
        s2 += __shfl_xor(s2, o, 64);
      }
      if ((lane & 15) == 0) {
        int row = wm * 64 + m * 16 + kq * 4 + j;
        part[wn][row][0] = s; part[wn][row][1] = s2;
      }
    }
  __syncthreads();
#pragma unroll
  for (int m = 0; m < 4; ++m)
#pragma unroll
    for (int j = 0; j < 4; ++j) {
      int row = wm * 64 + m * 16 + kq * 4 + j;
      float s = part[0][row][0] + part[1][row][0];
      float q2 = part[0][row][1] + part[1][row][1];
      float mean = s * (1.f / 128.f);
      float var = q2 * (1.f / 128.f) - mean * mean;
      float rstd = rsqrtf(var + EPSV);
      size_t R = (size_t)rowBase + row;
#pragma unroll
      for (int n = 0; n < 4; ++n) {
        float v = (acc[m][n][j] - mean) * rstd * gv[n] + bbv[n];
        v *= qpv[n];
        outp[R * EN + ecol + wn * 64 + n * 16 + lrow] = f2bf(v);
      }
    }
}

// Bilinear k-update GEMM: z = relu(A @ WbiT + qpart[b]) + kf  -> bf16
__global__ __launch_bounds__(256, 4) void gemm_bilin(
    const u16* __restrict__ A, const u16* __restrict__ BT,
    const float* __restrict__ biasB, const u16* __restrict__ resid,
    u16* __restrict__ out) {
  const int K = EN;
  __shared__ __align__(16) u16 As[2 * 128 * 32];
  __shared__ __align__(16) u16 Bs[2 * 128 * 32];
  int t = threadIdx.x;
  int w = t >> 6, lane = t & 63;
  int wm = w >> 1, wn = w & 1;

  int bid = blockIdx.x;                 // 3072 = 8 * 384
  int swz = ((bid & 7) * 384) + (bid >> 3);
  int rowT = swz / 6, cT = swz % 6;
  int rowBase = rowT << 7;
  int colBase = cT << 7;

  int koff = (((lane & 3) ^ ((lane >> 3) & 3)) << 3);
  const u16* gA = A + (size_t)(rowBase + (w << 5) + (lane >> 2)) * K + koff;
  const u16* gB = BT + (size_t)(colBase + (w << 5) + (lane >> 2)) * K + koff;

  int lrow = lane & 15, kq = lane >> 4;
  int sOff = ((kq ^ ((lrow >> 1) & 3)) << 3);
  f32x4 acc[4][4] = {};

  {
    u16* lA = As + (w << 10);
    u16* lB = Bs + (w << 10);
    gld16(gA, lA); gld16(gA + (size_t)16 * K, lA + 512);
    gld16(gB, lB); gld16(gB + (size_t)16 * K, lB + 512);
  }
  int buf = 0;
  for (int it = 0; it < 24; ++it) {
    __syncthreads();
    if (it < 23) {
      int k0 = (it + 1) << 5;
      u16* lA = As + ((buf ^ 1) << 12) + (w << 10);
      u16* lB = Bs + ((buf ^ 1) << 12) + (w << 10);
      gld16(gA + k0, lA); gld16(gA + (size_t)16 * K + k0, lA + 512);
      gld16(gB + k0, lB); gld16(gB + (size_t)16 * K + k0, lB + 512);
    }
    short8 af[4], bf[4];
#pragma unroll
    for (int m = 0; m < 4; ++m)
      af[m] = *(const short8*)&As[(buf << 12) + ((wm * 64 + m * 16 + lrow) << 5) + sOff];
#pragma unroll
    for (int n = 0; n < 4; ++n)
      bf[n] = *(const short8*)&Bs[(buf << 12) + ((wn * 64 + n * 16 + lrow) << 5) + sOff];
#pragma unroll
    for (int m = 0; m < 4; ++m)
#pragma unroll
      for (int n = 0; n < 4; ++n)
        acc[m][n] = __builtin_amdgcn_mfma_f32_16x16x32_bf16(af[m], bf[n], acc[m][n], 0, 0, 0);
    buf ^= 1;
  }

  const int bidx = rowBase >> 10;
  float qv[4];
#pragma unroll
  for (int n = 0; n < 4; ++n)
    qv[n] = biasB[(size_t)bidx * EN + colBase + wn * 64 + n * 16 + lrow];
#pragma unroll
  for (int m = 0; m < 4; ++m)
#pragma unroll
    for (int j = 0; j < 4; ++j) {
      int row = wm * 64 + m * 16 + kq * 4 + j;
      size_t R = (size_t)rowBase + row;
#pragma unroll
      for (int n = 0; n < 4; ++n) {
        int e = colBase + wn * 64 + n * 16 + lrow;
        float y = acc[m][n][j] + qv[n];
        y = fmaxf(y, 0.f) + bf2f(resid[R * EN + e]);
        out[R * EN + e] = f2bf(y);
      }
    }
}

// ---------------------------------------------------------------------------
// basic GEMM per (b,h,ltile): 128 l-rows x 64 cols, K=128.
__global__ __launch_bounds__(256) void gemm_basic(
    const u16* __restrict__ kpq, const u16* __restrict__ WabT,
    const float* __restrict__ bab, const float* __restrict__ Wal,
    const float* __restrict__ balp, const float* __restrict__ kmask,
    float* __restrict__ s_out, float* __restrict__ pool_part) {
  __shared__ __align__(16) char smem[128 * 65 * 4];
  __shared__ float km_sh[128];
  u16* As = (u16*)smem;            // [128][32]
  u16* Bs = (u16*)(smem + 8192);   // [64][32]
  int t = threadIdx.x, w = t >> 6, lane = t & 63;
  int lt = blockIdx.x, h = blockIdx.y, b = blockIdx.z;
  int lrow = lane & 15, kfr = (lane >> 4) << 3;
  int r0 = t >> 2, kb = (t & 3) << 3;
  if (t < 128) km_sh[t] = kmask[(size_t)b * LKN + lt * 128 + t];
  f32x4 acc[2][4] = {};
  size_t Abase = ((size_t)b * LKN + lt * 128) * EN + h * HDN;
  for (int k0 = 0; k0 < 128; k0 += 32) {
    *(short8*)&As[(r0 << 5) + kb] = *(const short8*)&kpq[Abase + (size_t)r0 * EN + k0 + kb];
    *(short8*)&As[((r0 + 64) << 5) + kb] = *(const short8*)&kpq[Abase + (size_t)(r0 + 64) * EN + k0 + kb];
    *(short8*)&Bs[(r0 << 5) + kb] = *(const short8*)&WabT[(size_t)r0 * 128 + k0 + kb];
    __syncthreads();
    short8 af[2], bfp[4];
#pragma unroll
    for (int m = 0; m < 2; ++m)
      af[m] = *(const short8*)&As[((w * 32 + m * 16 + lrow) << 5) + kfr];
#pragma unroll
    for (int n = 0; n < 4; ++n)
      bfp[n] = *(const short8*)&Bs[((n * 16 + lrow) << 5) + kfr];
#pragma unroll
    for (int m = 0; m < 2; ++m)
#pragma unroll
      for (int n = 0; n < 4; ++n)
        acc[m][n] = __builtin_amdgcn_mfma_f32_16x16x32_bf16(af[m], bfp[n], acc[m][n], 0, 0, 0);
    __syncthreads();
  }
  float* tile = (float*)smem;  // [128][65]
#pragma unroll
  for (int m = 0; m < 2; ++m)
#pragma unroll
    for (int n = 0; n < 4; ++n)
#pragma unroll
      for (int j = 0; j < 4; ++j) {
        int r = w * 32 + m * 16 + ((lane >> 4) << 2) + j;
        int c = n * 16 + lrow;
        tile[r * 65 + c] = fmaxf(acc[m][n][j] + bab[c], 0.f);
      }
  __syncthreads();
  if (t < 128) {
    float sum = 0.f;
    for (int c = 0; c < 64; ++c) sum += tile[t * 65 + c] * Wal[c];
    s_out[(((size_t)b * HN + h) << 10) + lt * 128 + t] = sum + balp[0];
  } else if (t < 192) {
    int c = t - 128;
    float p = 0.f;
    for (int r = 0; r < 128; ++r) p += tile[r * 65 + c] * km_sh[r];
    pool_part[((((size_t)b * HN + h) << 3) + lt) * 64 + c] = p;
  }
}

// softmax over LK (in place on s), pool finish, a_c = sigmoid(pool @ Wac + bac)
__global__ __launch_bounds__(256) void softmax_pool(
    float* __restrict__ s, const float* __restrict__ kmask,
    const float* __restrict__ msum, const float* __restrict__ pool_part,
    const float* __restrict__ Wac, const float* __restrict__ bac,
    float* __restrict__ a_c) {
  __shared__ float red[256];
  __shared__ float pool_sh[64];
  int t = threadIdx.x;
  int h = blockIdx.x, b = blockIdx.y;
  float* sb = s + (((size_t)b * HN + h) << 10);
  const float* km = kmask + (size_t)b * LKN;
  float v[4];
  float mx = -1e30f;
#pragma unroll
  for (int j = 0; j < 4; ++j) {
    int l = t * 4 + j;
    float x = sb[l];
    if (km[l] == 0.f) x = -1e9f;
    v[j] = x; mx = fmaxf(mx, x);
  }
  red[t] = mx; __syncthreads();
  for (int o = 128; o > 0; o >>= 1) { if (t < o) red[t] = fmaxf(red[t], red[t + o]); __syncthreads(); }
  float mxv = red[0];
  __syncthreads();
  float sum = 0.f;
#pragma unroll
  for (int j = 0; j < 4; ++j) { v[j] = expf(v[j] - mxv); sum += v[j]; }
  red[t] = sum; __syncthreads();
  for (int o = 128; o > 0; o >>= 1) { if (t < o) red[t] += red[t + o]; __syncthreads(); }
  float inv = 1.f / red[0];
#pragma unroll
  for (int j = 0; j < 4; ++j) sb[t * 4 + j] = v[j] * inv;
  if (t < 64) {
    float p = 0.f;
    for (int lt = 0; lt < 8; ++lt)
      p += pool_part[((((size_t)b * HN + h) << 3) + lt) * 64 + t];
    pool_sh[t] = p / msum[b];
  }
  __syncthreads();
  if (t < 128) {
    float acc = 0.f;
    for (int j = 0; j < 64; ++j) acc += pool_sh[j] * Wac[j * HDN + t];
    float x = acc + bac[t];
    a_c[(size_t)b * EN + h * HDN + t] = 1.f / (1.f + expf(-x));
  }
}

// v2a[b,h,d] = sum_l a_s[b,h,l] * v2[b*LK+l, h*128+d]
__global__ __launch_bounds__(256) void v2a_kernel(
    const float* __restrict__ a_s, const u16* __restrict__ v2,
    float* __restrict__ v2a) {
  __shared__ float part[256];
  int t = threadIdx.x;
  int d = t & 127, half = t >> 7;
  int h = blockIdx.x, b = blockIdx.y;
  const float* as = a_s + (((size_t)b * HN + h) << 10);
  const u16* vb = v2 + ((size_t)b * LKN) * EN + h * HDN + d;
  float acc = 0.f;
  for (int l = half; l < LKN; l += 2)
    acc += as[l] * bf2f(vb[(size_t)l * EN]);
  part[t] = acc; __syncthreads();
  if (t < 128) v2a[(size_t)b * EN + h * HDN + d] = part[t] + part[t + 128];
}

__global__ void qnext_kernel(
    const float* __restrict__ v1, const float* __restrict__ v2a,
    const float* __restrict__ a_c, float* __restrict__ q_cur,
    float* __restrict__ feats, int slot) {
  int idx = blockIdx.x * 256 + threadIdx.x;
  int b = idx / EN, e = idx % EN;
  float q = v1[idx] * v2a[idx] * a_c[idx];
  q_cur[idx] = q;
  feats[(size_t)b * 3 * EN + slot * EN + e] = q;
}

// row LN over 768 (bf16 in -> bf16 out)
__global__ __launch_bounds__(256) void ln_rows_kernel(
    const u16* __restrict__ z, const float* __restrict__ g,
    const float* __restrict__ bb, u16* __restrict__ outp) {
  __shared__ float red[256], red2[256];
  size_t R = blockIdx.x;
  int t = threadIdx.x;
  const u16* zr = z + R * EN;
  float x[3];
  float s = 0.f, s2 = 0.f;
#pragma unroll
  for (int j = 0; j < 3; ++j) { x[j] = bf2f(zr[j * 256 + t]); s += x[j]; s2 += x[j] * x[j]; }
  red[t] = s; red2[t] = s2; __syncthreads();
  for (int o = 128; o > 0; o >>= 1) {
    if (t < o) { red[t] += red[t + o]; red2[t] += red2[t + o]; }
    __syncthreads();
  }
  float m = red[0] * (1.f / EN), var = red2[0] * (1.f / EN) - m * m;
  float r = rsqrtf(var + EPSV);
#pragma unroll
  for (int j = 0; j < 3; ++j) {
    int e = j * 256 + t;
    outp[R * EN + e] = f2bf((x[j] - m) * r * g[e] + bb[e]);
  }
}

// final: out = ln(feats(B x 2304) @ Wp + bp)
__global__ __launch_bounds__(768) void final_kernel(
    const float* __restrict__ feats, const float* __restrict__ Wp,
    const float* __restrict__ bp, const float* __restrict__ g,
    const float* __restrict__ bb, float* __restrict__ outp) {
  __shared__ float fs[2304];
  __shared__ float red[24];
  __shared__ float mv[2];
  int t = threadIdx.x, b = blockIdx.x;
  fs[t] = feats[(size_t)b * 2304 + t];
  fs[t + 768] = feats[(size_t)b * 2304 + 768 + t];
  fs[t + 1536] = feats[(size_t)b * 2304 + 1536 + t];
  __syncthreads();
  float acc = 0.f;
  for (int k = 0; k < 2304; ++k) acc += fs[k] * Wp[(size_t)k * EN + t];
  float y = acc + bp[t];
  float s = y, s2 = y * y;
  for (int o = 32; o > 0; o >>= 1) { s += __shfl_down(s, o, 64); s2 += __shfl_down(s2, o, 64); }
  int wid = t >> 6, lane = t & 63;
  if (lane == 0) { red[wid] = s; red[12 + wid] = s2; }
  __syncthreads();
  if (t == 0) {
    float ts = 0.f, ts2 = 0.f;
    for (int i = 0; i < 12; ++i) { ts += red[i]; ts2 += red[12 + i]; }
    float m = ts * (1.f / EN), var = ts2 * (1.f / EN) - m * m;
    mv[0] = m; mv[1] = rsqrtf(var + EPSV);
  }
  __syncthreads();
  outp[(size_t)b * EN + t] = (y - mv[0]) * mv[1] * g[t] + bb[t];
}

// ---------------------------------------------------------------------------
extern "C" void kernel_launch(void* const* d_in, const int* in_sizes, int n_in,
                              void* d_out, int out_size, void* d_ws, size_t ws_size,
                              hipStream_t stream) {
  const float* q_feat = (const float*)d_in[0];
  const float* k_feats = (const float*)d_in[1];
  const float* q_mask = (const float*)d_in[2];
  const float* k_mask = (const float*)d_in[3];
  const float* Wq = (const float*)d_in[4];
  const float* bq = (const float*)d_in[5];
  const float* gq_g = (const float*)d_in[6];
  const float* gq_b = (const float*)d_in[7];
  const float* Wk = (const float*)d_in[8];
  const float* bk = (const float*)d_in[9];
  const float* gk_g = (const float*)d_in[10];
  const float* gk_b = (const float*)d_in[11];
  const float* Wv1 = (const float*)d_in[12];
  const float* bv1 = (const float*)d_in[13];
  const float* g1_g = (const float*)d_in[14];
  const float* g1_b = (const float*)d_in[15];
  const float* Wv2 = (const float*)d_in[16];
  const float* bv2 = (const float*)d_in[17];
  const float* g2_g = (const float*)d_in[18];
  const float* g2_b = (const float*)d_in[19];
  const float* Wab = (const float*)d_in[20];
  const float* bab = (const float*)d_in[21];
  const float* Wal = (const float*)d_in[22];
  const float* bal = (const float*)d_in[23];
  const float* Wac = (const float*)d_in[24];
  const float* bac = (const float*)d_in[25];
  const float* Wbi = (const float*)d_in[26];
  const float* bbi = (const float*)d_in[27];
  const float* lnb_g = (const float*)d_in[28];
  const float* lnb_b = (const float*)d_in[29];
  const float* Wp = (const float*)d_in[30];
  const float* bp = (const float*)d_in[31];
  const float* ln_g = (const float*)d_in[32];
  const float* ln_b = (const float*)d_in[33];
  float* out = (float*)d_out;
  (void)in_sizes; (void)n_in; (void)out_size; (void)ws_size;

  char* ws = (char*)d_ws;
  size_t off = 0;
  auto alloc = [&](size_t bytes) -> char* {
    char* p = ws + off;
    off += (bytes + 255) & ~(size_t)255;
    return p;
  };
  const size_t MK = (size_t)BB * LKN;  // 65536
  u16* kf = (u16*)alloc(MK * EN * 2);
  u16* kpq = (u16*)alloc(MK * EN * 2);   // also reused as z-buffer for k-update
  u16* v2b = (u16*)alloc(MK * EN * 2);
  u16* WkvT = (u16*)alloc((size_t)2 * 1536 * EN * 2);  // per layer: [Wk^T; Wv2^T]
  u16* WbiT = (u16*)alloc((size_t)EN * EN * 2);
  u16* WabT = (u16*)alloc((size_t)2 * D2N * HDN * 2);
  float* feats = (float*)alloc((size_t)BB * 3 * EN * 4);
  float* q_cur = (float*)alloc((size_t)BB * EN * 4);
  float* qp = (float*)alloc((size_t)BB * EN * 4);
  float* v1 = (float*)alloc((size_t)BB * EN * 4);
  float* qpart = (float*)alloc((size_t)BB * EN * 4);
  float* sbuf = (float*)alloc((size_t)BB * HN * LKN * 4);
  float* poolp = (float*)alloc((size_t)BB * HN * 8 * D2N * 4);
  float* a_c = (float*)alloc((size_t)BB * EN * 4);
  float* v2a = (float*)alloc((size_t)BB * EN * 4);
  float* msum = (float*)alloc((size_t)BB * 4);

  dim3 tb(32, 8);
  // weight prep (bf16 transposed copies)
  for (int i = 0; i < 2; ++i) {
    u16* dst = WkvT + (size_t)i * 1536 * EN;
    transpose_cvt<<<dim3(EN / 32, EN / 32), tb, 0, stream>>>(Wk + (size_t)i * EN * EN, dst, EN, EN);
    transpose_cvt<<<dim3(EN / 32, EN / 32), tb, 0, stream>>>(Wv2 + (size_t)i * EN * EN, dst + (size_t)EN * EN, EN, EN);
    transpose_cvt<<<dim3(HDN / 32, D2N / 32), tb, 0, stream>>>(Wab + (size_t)i * HDN * D2N, WabT + (size_t)i * D2N * HDN, HDN, D2N);
  }
  transpose_cvt<<<dim3(EN / 32, EN / 32), tb, 0, stream>>>(Wbi + (size_t)EN * EN, WbiT, EN, EN);

  conv_bf16<<<49152, 256, 0, stream>>>(k_feats, kf, MK * EN / 4);
  poolq_kernel<<<BB, EN, 0, stream>>>(q_feat, q_mask, q_cur, feats);
  msum_kernel<<<BB, 256, 0, stream>>>(k_mask, msum);

  for (int i = 0; i < 2; ++i) {
    const size_t wofs = (size_t)i * EN * EN;
    qside_kernel<<<BB, EN, 0, stream>>>(q_cur, Wq + wofs, bq + i * EN, gq_g + i * EN, gq_b + i * EN, qp);
    qside_kernel<<<BB, EN, 0, stream>>>(q_cur, Wv1 + wofs, bv1 + i * EN, g1_g + i * EN, g1_b + i * EN, v1);
    gemm_proj<<<6144, 256, 0, stream>>>(
        kf, WkvT + (size_t)i * 1536 * EN,
        bk + i * EN, gk_g + i * EN, gk_b + i * EN, qp, kpq,
        bv2 + i * EN, g2_g + i * EN, g2_b + i * EN, v2b);
    gemm_basic<<<dim3(8, HN, BB), 256, 0, stream>>>(kpq, WabT + (size_t)i * D2N * HDN, bab + i * D2N, Wal + i * D2N, bal + i, k_mask, sbuf, poolp);
    softmax_pool<<<dim3(HN, BB), 256, 0, stream>>>(sbuf, k_mask, msum, poolp, Wac + (size_t)i * D2N * HDN, bac + i * HDN, a_c);
    v2a_kernel<<<dim3(HN, BB), 256, 0, stream>>>(sbuf, v2b, v2a);
    qnext_kernel<<<BB * EN / 256, 256, 0, stream>>>(v1, v2a, a_c, q_cur, feats, i + 1);
    if (i == 0) {
      qpart_kernel<<<BB, EN, 0, stream>>>(q_cur, Wbi, bbi, qpart);
      gemm_bilin<<<3072, 256, 0, stream>>>(kf, WbiT, qpart, kf, kpq);
      ln_rows_kernel<<<MK, 256, 0, stream>>>(kpq, lnb_g, lnb_b, kf);
    }
  }
  final_kernel<<<BB, EN, 0, stream>>>(feats, Wp, bp, ln_g, ln_b, out);
}

// Round 4
// 1404.610 us; speedup vs baseline: 1.5201x; 1.0760x over previous
//
#include <hip/hip_runtime.h>
#include <math.h>

#define DEVI static __device__ __forceinline__

typedef unsigned short u16;
typedef __attribute__((ext_vector_type(8))) short short8;
typedef __attribute__((ext_vector_type(4))) float f32x4;

DEVI float bf2f(u16 u) { union { float f; unsigned int i; } c; c.i = ((unsigned int)u) << 16; return c.f; }
DEVI u16 f2bf(float f) {
  union { float f; unsigned int i; } c; c.f = f;
  unsigned int r = c.i + 0x7FFFu + ((c.i >> 16) & 1u);
  return (u16)(r >> 16);
}

DEVI float ftanh(float x) {
  float e = __expf(2.f * x);
  return 1.f - 2.f * __builtin_amdgcn_rcpf(e + 1.f);
}

// async global->LDS, 16B per lane. LDS base must be wave-uniform; HW adds lane*16B.
DEVI void gld16(const u16* g, u16* l) {
  __builtin_amdgcn_global_load_lds((const __attribute__((address_space(1))) unsigned int*)g,
                                   (__attribute__((address_space(3))) unsigned int*)l, 16, 0, 0);
}

#define BB 64
#define LQN 128
#define LKN 1024
#define EN 768
#define HN 6
#define HDN 128
#define D2N 64
#define EPSV 1e-5f

// ---------------------------------------------------------------------------
// transpose + fp32->bf16 convert: src (K x N) row-major -> dst (N x K) bf16
// z-batched: src += z*srcZ, dst += z*dstZ
__global__ __launch_bounds__(256) void transpose_cvt(
    const float* __restrict__ src, u16* __restrict__ dst, int K, int N,
    size_t srcZ, size_t dstZ) {
  __shared__ float tile[32][33];
  src += (size_t)blockIdx.z * srcZ;
  dst += (size_t)blockIdx.z * dstZ;
  int kb = blockIdx.x * 32, nb = blockIdx.y * 32;
  int tx = threadIdx.x, ty = threadIdx.y;  // 32 x 8
  for (int j = 0; j < 32; j += 8)
    tile[ty + j][tx] = src[(size_t)(kb + ty + j) * N + nb + tx];
  __syncthreads();
  for (int j = 0; j < 32; j += 8)
    dst[(size_t)(nb + ty + j) * K + kb + tx] = f2bf(tile[tx][ty + j]);
}

// elementwise fp32 -> bf16 (4 per thread)
__global__ void conv_bf16(const float* __restrict__ src, u16* __restrict__ dst, size_t n4) {
  size_t i = (size_t)blockIdx.x * 256 + threadIdx.x;
  if (i >= n4) return;
  float4 v = ((const float4*)src)[i];
  ushort4 o;
  o.x = f2bf(v.x); o.y = f2bf(v.y); o.z = f2bf(v.z); o.w = f2bf(v.w);
  ((ushort4*)dst)[i] = o;
}

// mean-pool q_feat over LQ -> q0; also write feats slot 0
__global__ __launch_bounds__(768) void poolq_kernel(
    const float* __restrict__ qf, const float* __restrict__ qm,
    float* __restrict__ q_cur, float* __restrict__ feats) {
  int t = threadIdx.x, b = blockIdx.x;
  float s = 0.f, ms = 0.f;
  for (int l = 0; l < LQN; ++l) {
    float w = qm[b * LQN + l];
    s += qf[((size_t)b * LQN + l) * EN + t] * w;
    ms += w;
  }
  float q = s / ms;
  q_cur[(size_t)b * EN + t] = q;
  feats[(size_t)b * 3 * EN + t] = q;
}

__global__ __launch_bounds__(256) void msum_kernel(const float* __restrict__ km, float* __restrict__ msum) {
  __shared__ float red[256];
  int t = threadIdx.x, b = blockIdx.x;
  float s = 0.f;
  for (int l = t; l < LKN; l += 256) s += km[b * LKN + l];
  red[t] = s; __syncthreads();
  for (int o = 128; o > 0; o >>= 1) { if (t < o) red[t] += red[t + o]; __syncthreads(); }
  if (t == 0) msum[b] = red[0];
}

// merged q-side projections: y-grid picks {Wq->qp} or {Wv1->v1}
__global__ __launch_bounds__(768) void qside2_kernel(
    const float* __restrict__ q_in,
    const float* __restrict__ W0, const float* __restrict__ b0,
    const float* __restrict__ g0, const float* __restrict__ bb0, float* __restrict__ o0,
    const float* __restrict__ W1, const float* __restrict__ b1,
    const float* __restrict__ g1, const float* __restrict__ bb1, float* __restrict__ o1) {
  __shared__ float qs[EN];
  __shared__ float ys[EN];
  __shared__ float mh[HN], rh[HN];
  int t = threadIdx.x, b = blockIdx.x, which = blockIdx.y;
  const float* W = which ? W1 : W0;
  const float* bvec = which ? b1 : b0;
  const float* g = which ? g1 : g0;
  const float* bb = which ? bb1 : bb0;
  float* outp = which ? o1 : o0;
  qs[t] = q_in[(size_t)b * EN + t];
  __syncthreads();
  float acc = 0.f;
  for (int k = 0; k < EN; ++k) acc += qs[k] * W[(size_t)k * EN + t];
  float y = tanhf(acc + bvec[t]);
  ys[t] = y; __syncthreads();
  if (t < HN) {
    float s = 0.f, s2 = 0.f;
    for (int d = 0; d < HDN; ++d) { float v = ys[t * HDN + d]; s += v; s2 += v * v; }
    float m = s * (1.f / HDN), var = s2 * (1.f / HDN) - m * m;
    mh[t] = m; rh[t] = rsqrtf(var + EPSV);
  }
  __syncthreads();
  int h = t >> 7;
  outp[(size_t)b * EN + t] = (y - mh[h]) * rh[h] * g[t] + bb[t];
}

// qpart = q @ Wbi[0:768,:] + bbi   (no activation)
__global__ __launch_bounds__(768) void qpart_kernel(
    const float* __restrict__ q_in, const float* __restrict__ W,
    const float* __restrict__ bbi, float* __restrict__ outp) {
  __shared__ float qs[EN];
  int t = threadIdx.x, b = blockIdx.x;
  qs[t] = q_in[(size_t)b * EN + t];
  __syncthreads();
  float acc = 0.f;
  for (int k = 0; k < EN; ++k) acc += qs[k] * W[(size_t)k * EN + t];
  outp[(size_t)b * EN + t] = acc + bbi[t];
}

// ---------------------------------------------------------------------------
// Merged projection GEMM: C(65536 x 1536) = A(65536 x 768 bf16) * [Wk^T; Wv2^T]
// Double-buffered global_load_lds staging, slot-XOR LDS swizzle, shuffle-GN
// epilogue. K-loop manually 2x-unrolled so buffer indices are compile-time.
__global__ __launch_bounds__(256, 4) void gemm_proj(
    const u16* __restrict__ A, const u16* __restrict__ BT,
    const float* __restrict__ bias_k, const float* __restrict__ g_k,
    const float* __restrict__ bb_k, const float* __restrict__ qp,
    u16* __restrict__ out_k,
    const float* __restrict__ bias_v, const float* __restrict__ g_v,
    const float* __restrict__ bb_v, u16* __restrict__ out_v) {
  const int K = EN;
  __shared__ __align__(16) u16 As[2 * 128 * 32];
  __shared__ __align__(16) u16 Bs[2 * 128 * 32];
  __shared__ float part[2][128][2];
  int t = threadIdx.x;
  int w = t >> 6, lane = t & 63;
  int wm = w >> 1, wn = w & 1;

  // XCD-chunked bijective swizzle: 6144 = 8 * 768
  int bid = blockIdx.x;
  int swz = ((bid & 7) * 768) + (bid >> 3);
  int rowT = swz / 12, cT = swz % 12;
  int rowBase = rowT << 7;

  // staging: lane covers row = w*32 + (lane>>2), slot = lane&3 (16B slots).
  // LDS[row][slot] holds global slot (slot ^ ((row>>1)&3))  [source pre-swizzle]
  int koff = (((lane & 3) ^ ((lane >> 3) & 3)) << 3);
  const u16* gA = A + (size_t)(rowBase + (w << 5) + (lane >> 2)) * K + koff;
  const u16* gB = BT + (size_t)((cT << 7) + (w << 5) + (lane >> 2)) * K + koff;

  int lrow = lane & 15, kq = lane >> 4;
  int sOff = ((kq ^ ((lrow >> 1) & 3)) << 3);  // swizzled k-slot for frag reads
  f32x4 acc[4][4] = {};

  u16* lA0b = As + (w << 10);
  u16* lB0b = Bs + (w << 10);
  u16* lA1b = As + 4096 + (w << 10);
  u16* lB1b = Bs + 4096 + (w << 10);

#define PROJ_PREF(LA, LB, k0) \
    { gld16(gA + (k0), LA); gld16(gA + (size_t)16 * K + (k0), LA + 512); \
      gld16(gB + (k0), LB); gld16(gB + (size_t)16 * K + (k0), LB + 512); }

#define PROJ_STEP(BASE) \
    { short8 af[4], bf[4]; \
      _Pragma("unroll") \
      for (int m = 0; m < 4; ++m) \
        af[m] = *(const short8*)&As[(BASE) + ((wm * 64 + m * 16 + lrow) << 5) + sOff]; \
      _Pragma("unroll") \
      for (int n = 0; n < 4; ++n) \
        bf[n] = *(const short8*)&Bs[(BASE) + ((wn * 64 + n * 16 + lrow) << 5) + sOff]; \
      _Pragma("unroll") \
      for (int m = 0; m < 4; ++m) \
        _Pragma("unroll") \
        for (int n = 0; n < 4; ++n) \
          acc[m][n] = __builtin_amdgcn_mfma_f32_16x16x32_bf16(af[m], bf[n], acc[m][n], 0, 0, 0); }

  PROJ_PREF(lA0b, lB0b, 0)
#pragma unroll 1
  for (int p = 0; p < 12; ++p) {
    __syncthreads();
    PROJ_PREF(lA1b, lB1b, (2 * p + 1) << 5)
    PROJ_STEP(0)
    __syncthreads();
    if (p < 11) PROJ_PREF(lA0b, lB0b, (2 * p + 2) << 5)
    PROJ_STEP(4096)
  }
#undef PROJ_PREF
#undef PROJ_STEP

  // ---- epilogue: y = tanh(acc + bias); GroupNorm over 128-col tile; write bf16
  const int which = cT >= 6;
  const int ecol = ((which ? cT - 6 : cT) << 7);
  const float* bias = which ? bias_v : bias_k;
  const float* gp = which ? g_v : g_k;
  const float* bbp = which ? bb_v : bb_k;
  u16* outp = which ? out_v : out_k;
  const int bidx = rowBase >> 10;

  float biasv[4], gv[4], bbv[4], qpv[4];
#pragma unroll
  for (int n = 0; n < 4; ++n) {
    int e = ecol + wn * 64 + n * 16 + lrow;
    biasv[n] = bias[e]; gv[n] = gp[e]; bbv[n] = bbp[e];
    qpv[n] = which ? 1.f : qp[(size_t)bidx * EN + e];
  }
#pragma unroll
  for (int m = 0; m < 4; ++m)
#pragma unroll
    for (int n = 0; n < 4; ++n)
#pragma unroll
      for (int j = 0; j < 4; ++j)
        acc[m][n][j] = ftanh(acc[m][n][j] + biasv[n]);

#pragma unroll
  for (int m = 0; m < 4; ++m)
#pragma unroll
    for (int j = 0; j < 4; ++j) {
      float s = acc[m][0][j] + acc[m][1][j] + acc[m][2][j] + acc[m][3][j];
      float s2 = acc[m][0][j] * acc[m][0][j] + acc[m][1][j] * acc[m][1][j] +
                 acc[m][2][j] * acc[m][2][j] + acc[m][3][j] * acc[m][3][j];
#pragma unroll
      for (int o = 1; o < 16; o <<= 1) {
        s += __shfl_xor(s, o, 64);
        s2 += __shfl_xor(s2, o, 64);
      }
      if ((lane & 15) == 0) {
        int row = wm * 64 + m * 16 + kq * 4 + j;
        part[wn][row][0] = s; part[wn][row][1] = s2;
      }
    }
  __syncthreads();
#pragma unroll
  for (int m = 0; m < 4; ++m)
#pragma unroll
    for (int j = 0; j < 4; ++j) {
      int row = wm * 64 + m * 16 + kq * 4 + j;
      float s = part[0][row][0] + part[1][row][0];
      float q2 = part[0][row][1] + part[1][row][1];
      float mean = s * (1.f / 128.f);
      float var = q2 * (1.f / 128.f) - mean * mean;
      float rstd = rsqrtf(var + EPSV);
      size_t R = (size_t)rowBase + row;
#pragma unroll
      for (int n = 0; n < 4; ++n) {
        float v = (acc[m][n][j] - mean) * rstd * gv[n] + bbv[n];
        v *= qpv[n];
        outp[R * EN + ecol + wn * 64 + n * 16 + lrow] = f2bf(v);
      }
    }
}

// Bilinear k-update GEMM: z = relu(A @ WbiT + qpart[b]) + kf  -> bf16
__global__ __launch_bounds__(256, 4) void gemm_bilin(
    const u16* __restrict__ A, const u16* __restrict__ BT,
    const float* __restrict__ biasB, const u16* __restrict__ resid,
    u16* __restrict__ out) {
  const int K = EN;
  __shared__ __align__(16) u16 As[2 * 128 * 32];
  __shared__ __align__(16) u16 Bs[2 * 128 * 32];
  int t = threadIdx.x;
  int w = t >> 6, lane = t & 63;
  int wm = w >> 1, wn = w & 1;

  int bid = blockIdx.x;                 // 3072 = 8 * 384
  int swz = ((bid & 7) * 384) + (bid >> 3);
  int rowT = swz / 6, cT = swz % 6;
  int rowBase = rowT << 7;
  int colBase = cT << 7;

  int koff = (((lane & 3) ^ ((lane >> 3) & 3)) << 3);
  const u16* gA = A + (size_t)(rowBase + (w << 5) + (lane >> 2)) * K + koff;
  const u16* gB = BT + (size_t)(colBase + (w << 5) + (lane >> 2)) * K + koff;

  int lrow = lane & 15, kq = lane >> 4;
  int sOff = ((kq ^ ((lrow >> 1) & 3)) << 3);
  f32x4 acc[4][4] = {};

  u16* lA0b = As + (w << 10);
  u16* lB0b = Bs + (w << 10);
  u16* lA1b = As + 4096 + (w << 10);
  u16* lB1b = Bs + 4096 + (w << 10);

#define BIL_PREF(LA, LB, k0) \
    { gld16(gA + (k0), LA); gld16(gA + (size_t)16 * K + (k0), LA + 512); \
      gld16(gB + (k0), LB); gld16(gB + (size_t)16 * K + (k0), LB + 512); }

#define BIL_STEP(BASE) \
    { short8 af[4], bf[4]; \
      _Pragma("unroll") \
      for (int m = 0; m < 4; ++m) \
        af[m] = *(const short8*)&As[(BASE) + ((wm * 64 + m * 16 + lrow) << 5) + sOff]; \
      _Pragma("unroll") \
      for (int n = 0; n < 4; ++n) \
        bf[n] = *(const short8*)&Bs[(BASE) + ((wn * 64 + n * 16 + lrow) << 5) + sOff]; \
      _Pragma("unroll") \
      for (int m = 0; m < 4; ++m) \
        _Pragma("unroll") \
        for (int n = 0; n < 4; ++n) \
          acc[m][n] = __builtin_amdgcn_mfma_f32_16x16x32_bf16(af[m], bf[n], acc[m][n], 0, 0, 0); }

  BIL_PREF(lA0b, lB0b, 0)
#pragma unroll 1
  for (int p = 0; p < 12; ++p) {
    __syncthreads();
    BIL_PREF(lA1b, lB1b, (2 * p + 1) << 5)
    BIL_STEP(0)
    __syncthreads();
    if (p < 11) BIL_PREF(lA0b, lB0b, (2 * p + 2) << 5)
    BIL_STEP(4096)
  }
#undef BIL_PREF
#undef BIL_STEP

  const int bidx = rowBase >> 10;
  float qv[4];
#pragma unroll
  for (int n = 0; n < 4; ++n)
    qv[n] = biasB[(size_t)bidx * EN + colBase + wn * 64 + n * 16 + lrow];
#pragma unroll
  for (int m = 0; m < 4; ++m)
#pragma unroll
    for (int j = 0; j < 4; ++j) {
      int row = wm * 64 + m * 16 + kq * 4 + j;
      size_t R = (size_t)rowBase + row;
#pragma unroll
      for (int n = 0; n < 4; ++n) {
        int e = colBase + wn * 64 + n * 16 + lrow;
        float y = acc[m][n][j] + qv[n];
        y = fmaxf(y, 0.f) + bf2f(resid[R * EN + e]);
        out[R * EN + e] = f2bf(y);
      }
    }
}

// ---------------------------------------------------------------------------
// basic GEMM per (b,h,ltile): basic = relu(kpq[128 l x 128 d] @ WabT[64 c x 128 d]^T + bab)
// gld16-staged, swizzled, shuffle-parallel epilogue: s=basic.Wal, pool partials.
__global__ __launch_bounds__(256) void gemm_basic(
    const u16* __restrict__ kpq, const u16* __restrict__ WabT,
    const float* __restrict__ bab, const float* __restrict__ Wal,
    const float* __restrict__ balp, const float* __restrict__ kmask,
    float* __restrict__ s_out, float* __restrict__ pool_part) {
  __shared__ __align__(16) u16 Bs[64 * 128];       // [c][128 k], slot-swizzled
  __shared__ __align__(16) u16 Ah[2][128 * 64];    // [l][64 k-half], slot-swizzled
  __shared__ float pool_sh[4][64];
  int t = threadIdx.x, w = t >> 6, lane = t & 63;
  int lt = blockIdx.x, h = blockIdx.y, b = blockIdx.z;
  int lrow = lane & 15, kq = lane >> 4;
  size_t Abase = ((size_t)b * LKN + lt * 128) * EN + h * HDN;

  // stage B (64x128, once) + A half0
  {
    int s4 = lane & 15, r4 = lane >> 4;
    const u16* Bg = WabT;
#pragma unroll
    for (int gi = 0; gi < 4; ++gi) {
      int r = w * 16 + gi * 4 + r4;
      int src = (s4 & 8) | ((s4 & 7) ^ (r & 7));
      gld16(Bg + (size_t)r * 128 + src * 8, Bs + (w * 16 + gi * 4) * 128);
    }
    int s8 = lane & 7, r8 = lane >> 3;
#pragma unroll
    for (int gi = 0; gi < 4; ++gi) {
      int r = w * 32 + gi * 8 + r8;
      int src = s8 ^ (r & 7);
      gld16(kpq + Abase + (size_t)r * EN + src * 8, Ah[0] + (w * 32 + gi * 8) * 64);
    }
  }
  __syncthreads();
  // stage A half1 (overlaps compute of half0)
  {
    int s8 = lane & 7, r8 = lane >> 3;
#pragma unroll
    for (int gi = 0; gi < 4; ++gi) {
      int r = w * 32 + gi * 8 + r8;
      int src = s8 ^ (r & 7);
      gld16(kpq + Abase + (size_t)r * EN + 64 + src * 8, Ah[1] + (w * 32 + gi * 8) * 64);
    }
  }
  f32x4 acc[2][4] = {};
#pragma unroll
  for (int ks = 0; ks < 2; ++ks) {
    short8 af[2], bf[4];
#pragma unroll
    for (int m = 0; m < 2; ++m)
      af[m] = *(const short8*)&Ah[0][(w * 32 + m * 16 + lrow) * 64 + (((ks * 4 + kq) ^ (lrow & 7)) << 3)];
#pragma unroll
    for (int n = 0; n < 4; ++n)
      bf[n] = *(const short8*)&Bs[(n * 16 + lrow) * 128 + (((ks * 4 + kq) ^ (lrow & 7)) << 3)];
#pragma unroll
    for (int m = 0; m < 2; ++m)
#pragma unroll
      for (int n = 0; n < 4; ++n)
        acc[m][n] = __builtin_amdgcn_mfma_f32_16x16x32_bf16(af[m], bf[n], acc[m][n], 0, 0, 0);
  }
  __syncthreads();
#pragma unroll
  for (int ks = 0; ks < 2; ++ks) {
    short8 af[2], bf[4];
#pragma unroll
    for (int m = 0; m < 2; ++m)
      af[m] = *(const short8*)&Ah[1][(w * 32 + m * 16 + lrow) * 64 + (((ks * 4 + kq) ^ (lrow & 7)) << 3)];
#pragma unroll
    for (int n = 0; n < 4; ++n)
      bf[n] = *(const short8*)&Bs[(n * 16 + lrow) * 128 + ((8 + ((ks * 4 + kq) ^ (lrow & 7))) << 3)];
#pragma unroll
    for (int m = 0; m < 2; ++m)
#pragma unroll
      for (int n = 0; n < 4; ++n)
        acc[m][n] = __builtin_amdgcn_mfma_f32_16x16x32_bf16(af[m], bf[n], acc[m][n], 0, 0, 0);
  }

  // epilogue: relu+bias; s = basic.Wal (reduce over c via lrow-shuffles);
  // pool[c] = sum_l basic*km (reduce over l via kq-shuffles + LDS cross-wave)
  float wv[4], bv[4];
#pragma unroll
  for (int n = 0; n < 4; ++n) { int c = n * 16 + lrow; wv[n] = Wal[c]; bv[n] = bab[c]; }
  float kmv[2][4];
  const float* km = kmask + (size_t)b * LKN + lt * 128;
#pragma unroll
  for (int m = 0; m < 2; ++m)
#pragma unroll
    for (int j = 0; j < 4; ++j) kmv[m][j] = km[w * 32 + m * 16 + kq * 4 + j];
  float balv = balp[0];
  float pp[4] = {0.f, 0.f, 0.f, 0.f};
#pragma unroll
  for (int m = 0; m < 2; ++m)
#pragma unroll
    for (int j = 0; j < 4; ++j) {
      float sp = 0.f;
#pragma unroll
      for (int n = 0; n < 4; ++n) {
        float bsv = fmaxf(acc[m][n][j] + bv[n], 0.f);
        sp += bsv * wv[n];
        pp[n] += bsv * kmv[m][j];
      }
      sp += __shfl_xor(sp, 1, 64);
      sp += __shfl_xor(sp, 2, 64);
      sp += __shfl_xor(sp, 4, 64);
      sp += __shfl_xor(sp, 8, 64);
      if (lrow == 0)
        s_out[(((size_t)b * HN + h) << 10) + lt * 128 + w * 32 + m * 16 + kq * 4 + j] = sp + balv;
    }
#pragma unroll
  for (int n = 0; n < 4; ++n) {
    pp[n] += __shfl_xor(pp[n], 16, 64);
    pp[n] += __shfl_xor(pp[n], 32, 64);
  }
  if (lane < 16) {
#pragma unroll
    for (int n = 0; n < 4; ++n) pool_sh[w][n * 16 + lane] = pp[n];
  }
  __syncthreads();
  if (t < 64) {
    float p = pool_sh[0][t] + pool_sh[1][t] + pool_sh[2][t] + pool_sh[3][t];
    pool_part[((((size_t)b * HN + h) << 3) + lt) * 64 + t] = p;
  }
}

// softmax over LK (in place on s), pool finish, a_c = sigmoid(pool @ Wac + bac)
__global__ __launch_bounds__(256) void softmax_pool(
    float* __restrict__ s, const float* __restrict__ kmask,
    const float* __restrict__ msum, const float* __restrict__ pool_part,
    const float* __restrict__ Wac, const float* __restrict__ bac,
    float* __restrict__ a_c) {
  __shared__ float red[256];
  __shared__ float pool_sh[64];
  int t = threadIdx.x;
  int h = blockIdx.x, b = blockIdx.y;
  float* sb = s + (((size_t)b * HN + h) << 10);
  const float* km = kmask + (size_t)b * LKN;
  float v[4];
  float mx = -1e30f;
#pragma unroll
  for (int j = 0; j < 4; ++j) {
    int l = t * 4 + j;
    float x = sb[l];
    if (km[l] == 0.f) x = -1e9f;
    v[j] = x; mx = fmaxf(mx, x);
  }
  red[t] = mx; __syncthreads();
  for (int o = 128; o > 0; o >>= 1) { if (t < o) red[t] = fmaxf(red[t], red[t + o]); __syncthreads(); }
  float mxv = red[0];
  __syncthreads();
  float sum = 0.f;
#pragma unroll
  for (int j = 0; j < 4; ++j) { v[j] = expf(v[j] - mxv); sum += v[j]; }
  red[t] = sum; __syncthreads();
  for (int o = 128; o > 0; o >>= 1) { if (t < o) red[t] += red[t + o]; __syncthreads(); }
  float inv = 1.f / red[0];
#pragma unroll
  for (int j = 0; j < 4; ++j) sb[t * 4 + j] = v[j] * inv;
  if (t < 64) {
    float p = 0.f;
    for (int lt = 0; lt < 8; ++lt)
      p += pool_part[((((size_t)b * HN + h) << 3) + lt) * 64 + t];
    pool_sh[t] = p / msum[b];
  }
  __syncthreads();
  if (t < 128) {
    float acc = 0.f;
    for (int j = 0; j < 64; ++j) acc += pool_sh[j] * Wac[j * HDN + t];
    float x = acc + bac[t];
    a_c[(size_t)b * EN + h * HDN + t] = 1.f / (1.f + expf(-x));
  }
}

// v2a[b,h,d] = sum_l a_s[b,h,l] * v2[b*LK+l, h*128+d]
__global__ __launch_bounds__(256) void v2a_kernel(
    const float* __restrict__ a_s, const u16* __restrict__ v2,
    float* __restrict__ v2a) {
  __shared__ float part[256];
  int t = threadIdx.x;
  int d = t & 127, half = t >> 7;
  int h = blockIdx.x, b = blockIdx.y;
  const float* as = a_s + (((size_t)b * HN + h) << 10);
  const u16* vb = v2 + ((size_t)b * LKN) * EN + h * HDN + d;
  float acc = 0.f;
  for (int l = half; l < LKN; l += 2)
    acc += as[l] * bf2f(vb[(size_t)l * EN]);
  part[t] = acc; __syncthreads();
  if (t < 128) v2a[(size_t)b * EN + h * HDN + d] = part[t] + part[t + 128];
}

__global__ void qnext_kernel(
    const float* __restrict__ v1, const float* __restrict__ v2a,
    const float* __restrict__ a_c, float* __restrict__ q_cur,
    float* __restrict__ feats, int slot) {
  int idx = blockIdx.x * 256 + threadIdx.x;
  int b = idx / EN, e = idx % EN;
  float q = v1[idx] * v2a[idx] * a_c[idx];
  q_cur[idx] = q;
  feats[(size_t)b * 3 * EN + slot * EN + e] = q;
}

// row LN over 768: wave-per-row, no LDS, vectorized (12 elems/lane)
__global__ __launch_bounds__(256) void ln_rows_kernel(
    const u16* __restrict__ z, const float* __restrict__ g,
    const float* __restrict__ bb, u16* __restrict__ outp) {
  int t = threadIdx.x, w = t >> 6, lane = t & 63;
  size_t R = (size_t)blockIdx.x * 4 + w;
  const u16* zr = z + R * EN;
  float xv[12];
  float s = 0.f, s2 = 0.f;
#pragma unroll
  for (int c = 0; c < 3; ++c) {
    ushort4 u = *(const ushort4*)&zr[c * 256 + lane * 4];
    float v0 = bf2f(u.x), v1 = bf2f(u.y), v2 = bf2f(u.z), v3 = bf2f(u.w);
    xv[c * 4 + 0] = v0; xv[c * 4 + 1] = v1; xv[c * 4 + 2] = v2; xv[c * 4 + 3] = v3;
    s += v0 + v1 + v2 + v3;
    s2 += v0 * v0 + v1 * v1 + v2 * v2 + v3 * v3;
  }
#pragma unroll
  for (int o = 1; o < 64; o <<= 1) { s += __shfl_xor(s, o, 64); s2 += __shfl_xor(s2, o, 64); }
  float m = s * (1.f / EN), var = s2 * (1.f / EN) - m * m;
  float r = rsqrtf(var + EPSV);
#pragma unroll
  for (int c = 0; c < 3; ++c) {
    ushort4 o4;
    int e = c * 256 + lane * 4;
    o4.x = f2bf((xv[c * 4 + 0] - m) * r * g[e + 0] + bb[e + 0]);
    o4.y = f2bf((xv[c * 4 + 1] - m) * r * g[e + 1] + bb[e + 1]);
    o4.z = f2bf((xv[c * 4 + 2] - m) * r * g[e + 2] + bb[e + 2]);
    o4.w = f2bf((xv[c * 4 + 3] - m) * r * g[e + 3] + bb[e + 3]);
    *(ushort4*)&outp[R * EN + e] = o4;
  }
}

// final: out = ln(feats(B x 2304) @ Wp + bp)
__global__ __launch_bounds__(768) void final_kernel(
    const float* __restrict__ feats, const float* __restrict__ Wp,
    const float* __restrict__ bp, const float* __restrict__ g,
    const float* __restrict__ bb, float* __restrict__ outp) {
  __shared__ float fs[2304];
  __shared__ float red[24];
  __shared__ float mv[2];
  int t = threadIdx.x, b = blockIdx.x;
  fs[t] = feats[(size_t)b * 2304 + t];
  fs[t + 768] = feats[(size_t)b * 2304 + 768 + t];
  fs[t + 1536] = feats[(size_t)b * 2304 + 1536 + t];
  __syncthreads();
  float acc = 0.f;
  for (int k = 0; k < 2304; ++k) acc += fs[k] * Wp[(size_t)k * EN + t];
  float y = acc + bp[t];
  float s = y, s2 = y * y;
  for (int o = 32; o > 0; o >>= 1) { s += __shfl_down(s, o, 64); s2 += __shfl_down(s2, o, 64); }
  int wid = t >> 6, lane = t & 63;
  if (lane == 0) { red[wid] = s; red[12 + wid] = s2; }
  __syncthreads();
  if (t == 0) {
    float ts = 0.f, ts2 = 0.f;
    for (int i = 0; i < 12; ++i) { ts += red[i]; ts2 += red[12 + i]; }
    float m = ts * (1.f / EN), var = ts2 * (1.f / EN) - m * m;
    mv[0] = m; mv[1] = rsqrtf(var + EPSV);
  }
  __syncthreads();
  outp[(size_t)b * EN + t] = (y - mv[0]) * mv[1] * g[t] + bb[t];
}

// ---------------------------------------------------------------------------
extern "C" void kernel_launch(void* const* d_in, const int* in_sizes, int n_in,
                              void* d_out, int out_size, void* d_ws, size_t ws_size,
                              hipStream_t stream) {
  const float* q_feat = (const float*)d_in[0];
  const float* k_feats = (const float*)d_in[1];
  const float* q_mask = (const float*)d_in[2];
  const float* k_mask = (const float*)d_in[3];
  const float* Wq = (const float*)d_in[4];
  const float* bq = (const float*)d_in[5];
  const float* gq_g = (const float*)d_in[6];
  const float* gq_b = (const float*)d_in[7];
  const float* Wk = (const float*)d_in[8];
  const float* bk = (const float*)d_in[9];
  const float* gk_g = (const float*)d_in[10];
  const float* gk_b = (const float*)d_in[11];
  const float* Wv1 = (const float*)d_in[12];
  const float* bv1 = (const float*)d_in[13];
  const float* g1_g = (const float*)d_in[14];
  const float* g1_b = (const float*)d_in[15];
  const float* Wv2 = (const float*)d_in[16];
  const float* bv2 = (const float*)d_in[17];
  const float* g2_g = (const float*)d_in[18];
  const float* g2_b = (const float*)d_in[19];
  const float* Wab = (const float*)d_in[20];
  const float* bab = (const float*)d_in[21];
  const float* Wal = (const float*)d_in[22];
  const float* bal = (const float*)d_in[23];
  const float* Wac = (const float*)d_in[24];
  const float* bac = (const float*)d_in[25];
  const float* Wbi = (const float*)d_in[26];
  const float* bbi = (const float*)d_in[27];
  const float* lnb_g = (const float*)d_in[28];
  const float* lnb_b = (const float*)d_in[29];
  const float* Wp = (const float*)d_in[30];
  const float* bp = (const float*)d_in[31];
  const float* ln_g = (const float*)d_in[32];
  const float* ln_b = (const float*)d_in[33];
  float* out = (float*)d_out;
  (void)in_sizes; (void)n_in; (void)out_size; (void)ws_size;

  char* ws = (char*)d_ws;
  size_t off = 0;
  auto alloc = [&](size_t bytes) -> char* {
    char* p = ws + off;
    off += (bytes + 255) & ~(size_t)255;
    return p;
  };
  const size_t MK = (size_t)BB * LKN;  // 65536
  u16* kf = (u16*)alloc(MK * EN * 2);
  u16* kpq = (u16*)alloc(MK * EN * 2);   // also reused as z-buffer for k-update
  u16* v2b = (u16*)alloc(MK * EN * 2);
  u16* WkvT = (u16*)alloc((size_t)2 * 1536 * EN * 2);  // per layer: [Wk^T; Wv2^T]
  u16* WbiT = (u16*)alloc((size_t)EN * EN * 2);
  u16* WabT = (u16*)alloc((size_t)2 * D2N * HDN * 2);
  float* feats = (float*)alloc((size_t)BB * 3 * EN * 4);
  float* q_cur = (float*)alloc((size_t)BB * EN * 4);
  float* qp = (float*)alloc((size_t)BB * EN * 4);
  float* v1 = (float*)alloc((size_t)BB * EN * 4);
  float* qpart = (float*)alloc((size_t)BB * EN * 4);
  float* sbuf = (float*)alloc((size_t)BB * HN * LKN * 4);
  float* poolp = (float*)alloc((size_t)BB * HN * 8 * D2N * 4);
  float* a_c = (float*)alloc((size_t)BB * EN * 4);
  float* v2a = (float*)alloc((size_t)BB * EN * 4);
  float* msum = (float*)alloc((size_t)BB * 4);

  dim3 tb(32, 8);
  // weight prep (bf16 transposed copies), z-batched
  transpose_cvt<<<dim3(24, 24, 2), tb, 0, stream>>>(Wk, WkvT, EN, EN, (size_t)EN * EN, (size_t)1536 * EN);
  transpose_cvt<<<dim3(24, 24, 2), tb, 0, stream>>>(Wv2, WkvT + (size_t)EN * EN, EN, EN, (size_t)EN * EN, (size_t)1536 * EN);
  transpose_cvt<<<dim3(24, 24, 1), tb, 0, stream>>>(Wbi + (size_t)EN * EN, WbiT, EN, EN, 0, 0);
  transpose_cvt<<<dim3(4, 2, 2), tb, 0, stream>>>(Wab, WabT, HDN, D2N, (size_t)HDN * D2N, (size_t)D2N * HDN);

  conv_bf16<<<49152, 256, 0, stream>>>(k_feats, kf, MK * EN / 4);
  poolq_kernel<<<BB, EN, 0, stream>>>(q_feat, q_mask, q_cur, feats);
  msum_kernel<<<BB, 256, 0, stream>>>(k_mask, msum);

  for (int i = 0; i < 2; ++i) {
    const size_t wofs = (size_t)i * EN * EN;
    qside2_kernel<<<dim3(BB, 2), 768, 0, stream>>>(
        q_cur, Wq + wofs, bq + i * EN, gq_g + i * EN, gq_b + i * EN, qp,
        Wv1 + wofs, bv1 + i * EN, g1_g + i * EN, g1_b + i * EN, v1);
    gemm_proj<<<6144, 256, 0, stream>>>(
        kf, WkvT + (size_t)i * 1536 * EN,
        bk + i * EN, gk_g + i * EN, gk_b + i * EN, qp, kpq,
        bv2 + i * EN, g2_g + i * EN, g2_b + i * EN, v2b);
    gemm_basic<<<dim3(8, HN, BB), 256, 0, stream>>>(kpq, WabT + (size_t)i * D2N * HDN, bab + i * D2N, Wal + i * D2N, bal + i, k_mask, sbuf, poolp);
    softmax_pool<<<dim3(HN, BB), 256, 0, stream>>>(sbuf, k_mask, msum, poolp, Wac + (size_t)i * D2N * HDN, bac + i * HDN, a_c);
    v2a_kernel<<<dim3(HN, BB), 256, 0, stream>>>(sbuf, v2b, v2a);
    qnext_kernel<<<BB * EN / 256, 256, 0, stream>>>(v1, v2a, a_c, q_cur, feats, i + 1);
    if (i == 0) {
      qpart_kernel<<<BB, EN, 0, stream>>>(q_cur, Wbi, bbi, qpart);
      gemm_bilin<<<3072, 256, 0, stream>>>(kf, WbiT, qpart, kf, kpq);
      ln_rows_kernel<<<MK / 4, 256, 0, stream>>>(kpq, lnb_g, lnb_b, kf);
    }
  }
  final_kernel<<<BB, EN, 0, stream>>>(feats, Wp, bp, ln_g, ln_b, out);
}